// Round 1
// baseline (1262.981 us; speedup 1.0000x reference)
//
#include <hip/hip_runtime.h>
#include <math.h>

#define BSZ 4096

// ---------------------------------------------------------------------------
// GEMM: C[m,n] = act(sum_k A[m,k]*W[n,k] + bias[n]); A:[M,K] row-major,
// W:[N,K] row-major (torch Linear weight). M,N multiples of 64; any K.
// ---------------------------------------------------------------------------
__global__ void gemm_kernel(const float* __restrict__ A, const float* __restrict__ W,
                            const float* __restrict__ bias, float* __restrict__ C,
                            int M, int N, int K, int relu) {
    __shared__ float As[16][65];
    __shared__ float Ws[16][65];
    const int tx = threadIdx.x, ty = threadIdx.y;
    const int tid = ty * 16 + tx;
    const int m0 = blockIdx.y * 64, n0 = blockIdx.x * 64;
    float acc[4][4] = {};
    const int lrow = tid >> 2;
    const int lkb = (tid & 3) * 4;
    for (int k0 = 0; k0 < K; k0 += 16) {
#pragma unroll
        for (int u = 0; u < 4; ++u) {
            int k = k0 + lkb + u;
            As[lkb + u][lrow] = (k < K) ? A[(size_t)(m0 + lrow) * K + k] : 0.0f;
            Ws[lkb + u][lrow] = (k < K) ? W[(size_t)(n0 + lrow) * K + k] : 0.0f;
        }
        __syncthreads();
#pragma unroll
        for (int kk = 0; kk < 16; ++kk) {
            float av[4], bv[4];
#pragma unroll
            for (int i = 0; i < 4; ++i) av[i] = As[kk][ty * 4 + i];
#pragma unroll
            for (int j = 0; j < 4; ++j) bv[j] = Ws[kk][tx * 4 + j];
#pragma unroll
            for (int i = 0; i < 4; ++i)
#pragma unroll
                for (int j = 0; j < 4; ++j) acc[i][j] += av[i] * bv[j];
        }
        __syncthreads();
    }
#pragma unroll
    for (int i = 0; i < 4; ++i)
#pragma unroll
        for (int j = 0; j < 4; ++j) {
            int n = n0 + tx * 4 + j;
            float v = acc[i][j] + bias[n];
            if (relu) v = fmaxf(v, 0.0f);
            C[(size_t)(m0 + ty * 4 + i) * N + n] = v;
        }
}

// ---------------------------------------------------------------------------
// Row-normalize: Y[m,:] = X[m,:] / max(||X[m,:]||, 1e-12), rows of length 128.
// ---------------------------------------------------------------------------
__global__ void rownorm_kernel(const float* __restrict__ X, float* __restrict__ Y) {
    int m = blockIdx.x * blockDim.x + threadIdx.x;
    if (m >= BSZ) return;
    const float4* xp = (const float4*)(X + (size_t)m * 128);
    float ss = 0.0f;
#pragma unroll
    for (int u = 0; u < 32; ++u) {
        float4 v = xp[u];
        ss += v.x * v.x + v.y * v.y + v.z * v.z + v.w * v.w;
    }
    float nrm = sqrtf(ss);
    float inv = 1.0f / fmaxf(nrm, 1e-12f);
    float4* yp = (float4*)(Y + (size_t)m * 128);
#pragma unroll
    for (int u = 0; u < 32; ++u) {
        float4 v = xp[u];
        v.x *= inv; v.y *= inv; v.z *= inv; v.w *= inv;
        yp[u] = v;
    }
}

// ---------------------------------------------------------------------------
// Scalar head: out[m] = dot(X[m,:128], w) + b[0]
// ---------------------------------------------------------------------------
__global__ void head_kernel(const float* __restrict__ X, const float* __restrict__ w,
                            const float* __restrict__ b, float* __restrict__ out) {
    int m = blockIdx.x * blockDim.x + threadIdx.x;
    if (m >= BSZ) return;
    const float4* xp = (const float4*)(X + (size_t)m * 128);
    const float4* wp = (const float4*)w;
    float acc = 0.0f;
#pragma unroll
    for (int u = 0; u < 32; ++u) {
        float4 a = xp[u], c = wp[u];
        acc += a.x * c.x + a.y * c.y + a.z * c.z + a.w * c.w;
    }
    out[m] = acc + b[0];
}

// ---------------------------------------------------------------------------
// Count y==0 -> scal[0] (float)
// ---------------------------------------------------------------------------
__global__ void county_kernel(const int* __restrict__ y, float* __restrict__ scal) {
    __shared__ int red[256];
    int t = threadIdx.x;
    int c = 0;
    for (int i = t; i < BSZ; i += 256) c += (y[i] == 0) ? 1 : 0;
    red[t] = c;
    __syncthreads();
    for (int s = 128; s > 0; s >>= 1) {
        if (t < s) red[t] += red[t + s];
        __syncthreads();
    }
    if (t == 0) scal[0] = (float)red[0];
}

// ---------------------------------------------------------------------------
// CLIP tile pass: S = In @ Tn^T (4096x4096, K=128) in 64x64 tiles.
// Accumulates 10 stat arrays (each 4096) into st via atomics:
//  rows (scaled logits L=s*S):  [0]=Z1=sum e^L  [1]=F1=sum e^L*L
//  [2]=W1=sum_same e^L  [3]=Sr=sum S  [4]=SSr=sum_same S
//  cols (unscaled S^T dir):     [5]=Z2=sum e^S  [6]=E2=sum e^S*S
//  [7]=W2=sum_same e^S  [8]=Sc=sum S  [9]=SSc=sum_same S
// ---------------------------------------------------------------------------
__global__ void clip_tile_kernel(const float* __restrict__ In, const float* __restrict__ Tn,
                                 const int* __restrict__ y, const float* __restrict__ scale_log,
                                 float* __restrict__ st) {
    __shared__ float Ia[64][36];
    __shared__ float Tb[64][36];
    __shared__ float red[64][17];
    const int tx = threadIdx.x, ty = threadIdx.y;
    const int tid = ty * 16 + tx;
    const int r0 = blockIdx.y * 64, c0 = blockIdx.x * 64;
    float acc[4][4] = {};
    for (int k0 = 0; k0 < 128; k0 += 32) {
#pragma unroll
        for (int r = 0; r < 2; ++r) {
            int idx = tid * 2 + r;
            int row = idx >> 3;
            int c4 = (idx & 7) * 4;
            *(float4*)&Ia[row][c4] = *(const float4*)&In[(size_t)(r0 + row) * 128 + k0 + c4];
            *(float4*)&Tb[row][c4] = *(const float4*)&Tn[(size_t)(c0 + row) * 128 + k0 + c4];
        }
        __syncthreads();
#pragma unroll
        for (int kk = 0; kk < 32; ++kk) {
            float av[4], bv[4];
#pragma unroll
            for (int i = 0; i < 4; ++i) av[i] = Ia[ty * 4 + i][kk];
#pragma unroll
            for (int j = 0; j < 4; ++j) bv[j] = Tb[tx * 4 + j][kk];
#pragma unroll
            for (int i = 0; i < 4; ++i)
#pragma unroll
                for (int j = 0; j < 4; ++j) acc[i][j] += av[i] * bv[j];
        }
        __syncthreads();
    }

    const float s = expf(scale_log[0]);
    int yr[4], yc[4];
#pragma unroll
    for (int i = 0; i < 4; ++i) yr[i] = y[r0 + ty * 4 + i];
#pragma unroll
    for (int j = 0; j < 4; ++j) yc[j] = y[c0 + tx * 4 + j];

    float rv[5][4] = {};  // Z1,F1,W1,Sr,SSr per local row
    float cv[5][4] = {};  // Z2,E2,W2,Sc,SSc per local col
#pragma unroll
    for (int i = 0; i < 4; ++i)
#pragma unroll
        for (int j = 0; j < 4; ++j) {
            float S = acc[i][j];
            float L = s * S;
            float e1 = expf(L);
            float e2 = expf(S);
            bool same = (yr[i] == yc[j]);
            rv[0][i] += e1; rv[1][i] += e1 * L; rv[3][i] += S;
            cv[0][j] += e2; cv[1][j] += e2 * S; cv[3][j] += S;
            if (same) { rv[2][i] += e1; rv[4][i] += S; cv[2][j] += e2; cv[4][j] += S; }
        }

#pragma unroll
    for (int q = 0; q < 5; ++q) {
#pragma unroll
        for (int i = 0; i < 4; ++i) red[ty * 4 + i][tx] = rv[q][i];
        __syncthreads();
        if (tid < 64) {
            float ssum = 0.0f;
#pragma unroll
            for (int t = 0; t < 16; ++t) ssum += red[tid][t];
            atomicAdd(&st[(size_t)q * BSZ + r0 + tid], ssum);
        }
        __syncthreads();
#pragma unroll
        for (int j = 0; j < 4; ++j) red[tx * 4 + j][ty] = cv[q][j];
        __syncthreads();
        if (tid < 64) {
            float ssum = 0.0f;
#pragma unroll
            for (int t = 0; t < 16; ++t) ssum += red[tid][t];
            atomicAdd(&st[(size_t)(5 + q) * BSZ + c0 + tid], ssum);
        }
        __syncthreads();
    }
}

// ---------------------------------------------------------------------------
// CLIP finalize: combine stats into loss scalar (atomicAdd to loss_slot).
// For each index k: row term (scaled dir) + col term (unscaled transpose dir).
// kl_p_q + kl_q_p per row: Qlq - s*QS + F/Z - lq_d - (lq_s-lq_d)*W/Z  (logZ cancels)
// ---------------------------------------------------------------------------
__global__ void clip_finalize_kernel(const float* __restrict__ st, const int* __restrict__ y,
                                     const float* __restrict__ scale_log,
                                     const float* __restrict__ scal, float* __restrict__ loss_slot) {
    __shared__ float red[256];
    int k = blockIdx.x * 256 + threadIdx.x;
    const float Bf = (float)BSZ;
    const float s = expf(scale_log[0]);
    const float n0 = scal[0];
    int yk = y[k];
    float n = (yk == 0) ? n0 : (Bf - n0);
    float a = 1.0f / n;
    float ea = expf(a);
    float denom = n * ea + (Bf - n);
    float q_s = ea / denom, q_d = 1.0f / denom;
    float ld = logf(denom);
    float lq_s = a - ld, lq_d = -ld;
    float Qlq = n * q_s * lq_s + (Bf - n) * q_d * lq_d;

    float Z1 = st[0 * BSZ + k], F1 = st[1 * BSZ + k], W1 = st[2 * BSZ + k];
    float Sr = st[3 * BSZ + k], SSr = st[4 * BSZ + k];
    float QS1 = q_d * Sr + (q_s - q_d) * SSr;
    float term_r = Qlq - s * QS1 + F1 / Z1 - lq_d - (lq_s - lq_d) * (W1 / Z1);

    float Z2 = st[5 * BSZ + k], E2 = st[6 * BSZ + k], W2 = st[7 * BSZ + k];
    float Sc = st[8 * BSZ + k], SSc = st[9 * BSZ + k];
    float QS2 = q_d * Sc + (q_s - q_d) * SSc;
    float term_c = Qlq - QS2 + E2 / Z2 - lq_d - (lq_s - lq_d) * (W2 / Z2);

    float v = (term_r + term_c) / (4.0f * Bf);
    int t = threadIdx.x;
    red[t] = v;
    __syncthreads();
    for (int ss2 = 128; ss2 > 0; ss2 >>= 1) {
        if (t < ss2) red[t] += red[t + ss2];
        __syncthreads();
    }
    if (t == 0) atomicAdd(loss_slot, red[0]);
}

// ---------------------------------------------------------------------------
// Gram: G[a,b] += sum_{m in chunk} A[m,a]*A[m,b]; A:[4096,128], G:[128,128]
// grid (8,8,16), block (16,16)
// ---------------------------------------------------------------------------
__global__ void gram_kernel(const float* __restrict__ A, float* __restrict__ G) {
    int a = blockIdx.y * 16 + threadIdx.y;
    int b = blockIdx.x * 16 + threadIdx.x;
    int m0 = blockIdx.z * 256;
    float acc = 0.0f;
    for (int m = m0; m < m0 + 256; ++m)
        acc += A[(size_t)m * 128 + a] * A[(size_t)m * 128 + b];
    atomicAdd(&G[a * 128 + b], acc);
}

// ---------------------------------------------------------------------------
// frob_dot: slot += sum(GA .* GB) over 128x128
// ---------------------------------------------------------------------------
__global__ void frob_dot_kernel(const float* __restrict__ GA, const float* __restrict__ GB,
                                float* __restrict__ slot) {
    __shared__ float red[256];
    int t = threadIdx.x;
    float acc = 0.0f;
    for (int u = blockIdx.x * 256 + t; u < 16384; u += gridDim.x * 256)
        acc += GA[u] * GB[u];
    red[t] = acc;
    __syncthreads();
    for (int s = 128; s > 0; s >>= 1) {
        if (t < s) red[t] += red[t + s];
        __syncthreads();
    }
    if (t == 0) atomicAdd(slot, red[0]);
}

// ---------------------------------------------------------------------------
// Final combine: out[0] = ((sqrt(ss_t)+sqrt(ss_i))/2 + loss_sh + loss1) / 3
// ---------------------------------------------------------------------------
__global__ void final_kernel(const float* __restrict__ scal, float* __restrict__ out) {
    float loss1 = scal[1];
    float loss_sh = scal[2];
    float ss_i = scal[3];
    float ss_t = scal[4];
    float loss_sp = 0.5f * (sqrtf(ss_t) + sqrtf(ss_i));
    out[0] = (loss_sp + loss_sh + loss1) / 3.0f;
}

// ---------------------------------------------------------------------------
extern "C" void kernel_launch(void* const* d_in, const int* in_sizes, int n_in,
                              void* d_out, int out_size, void* d_ws, size_t ws_size,
                              hipStream_t stream) {
    const float* i_in  = (const float*)d_in[0];
    const float* t_in  = (const float*)d_in[1];
    const int*   y     = (const int*)d_in[2];
    const float* l1_w  = (const float*)d_in[3];
    const float* l1_b  = (const float*)d_in[4];
    const float* l2_w  = (const float*)d_in[5];
    const float* l2_b  = (const float*)d_in[6];
    const float* l3_w  = (const float*)d_in[7];
    const float* l3_b  = (const float*)d_in[8];
    const float* tl1_w = (const float*)d_in[9];
    const float* tl1_b = (const float*)d_in[10];
    const float* tl2_w = (const float*)d_in[11];
    const float* tl2_b = (const float*)d_in[12];
    const float* isp_w = (const float*)d_in[13];
    const float* isp_b = (const float*)d_in[14];
    const float* ish_w = (const float*)d_in[15];
    const float* ish_b = (const float*)d_in[16];
    const float* tsh_w = (const float*)d_in[17];
    const float* tsh_b = (const float*)d_in[18];
    const float* tsp_w = (const float*)d_in[19];
    const float* tsp_b = (const float*)d_in[20];
    const float* c1_w  = (const float*)d_in[21];
    const float* c1_b  = (const float*)d_in[22];
    const float* c2_w  = (const float*)d_in[23];
    const float* c2_b  = (const float*)d_in[24];
    const float* c3_w  = (const float*)d_in[25];
    const float* c3_b  = (const float*)d_in[26];
    const float* c4_w  = (const float*)d_in[27];
    const float* c4_b  = (const float*)d_in[28];
    const float* scale1 = (const float*)d_in[29];
    const float* scale2 = (const float*)d_in[30];

    float* ws = (float*)d_ws;
    // zeroed region
    float* SCAL = ws + 0;              // 64
    float* ST1  = ws + 64;             // 10*4096
    float* ST2  = ST1 + 10 * BSZ;      // 10*4096
    float* GA   = ST2 + 10 * BSZ;      // 16384
    float* GB   = GA + 16384;
    float* GC   = GB + 16384;
    float* GD   = GC + 16384;
    size_t zero_floats = 64 + 20 * BSZ + 4 * 16384;
    // work buffers
    float* FI1  = GD + 16384;                       // 4096*512
    float* FI2  = FI1 + (size_t)BSZ * 512;          // 4096*256
    float* FI   = FI2 + (size_t)BSZ * 256;          // 4096*128
    float* FT1  = FI  + (size_t)BSZ * 128;
    float* FT   = FT1 + (size_t)BSZ * 128;
    float* ISP  = FT  + (size_t)BSZ * 128;
    float* ISH  = ISP + (size_t)BSZ * 128;
    float* TSH  = ISH + (size_t)BSZ * 128;
    float* TSP  = TSH + (size_t)BSZ * 128;
    float* FIN  = TSP + (size_t)BSZ * 128;
    float* FTN  = FIN + (size_t)BSZ * 128;
    float* ISHN = FTN + (size_t)BSZ * 128;
    float* TSHN = ISHN + (size_t)BSZ * 128;

    float* out = (float*)d_out;

    hipMemsetAsync(d_ws, 0, zero_floats * sizeof(float), stream);
    county_kernel<<<1, 256, 0, stream>>>(y, SCAL);

    dim3 blk(16, 16);
    // MLP chains
    gemm_kernel<<<dim3(512 / 64, 64), blk, 0, stream>>>(i_in, l1_w, l1_b, FI1, BSZ, 512, 2048, 1);
    gemm_kernel<<<dim3(256 / 64, 64), blk, 0, stream>>>(FI1, l2_w, l2_b, FI2, BSZ, 256, 512, 1);
    gemm_kernel<<<dim3(128 / 64, 64), blk, 0, stream>>>(FI2, l3_w, l3_b, FI, BSZ, 128, 256, 0);
    gemm_kernel<<<dim3(128 / 64, 64), blk, 0, stream>>>(t_in, tl1_w, tl1_b, FT1, BSZ, 128, 49, 1);
    gemm_kernel<<<dim3(128 / 64, 64), blk, 0, stream>>>(FT1, tl2_w, tl2_b, FT, BSZ, 128, 128, 0);
    // SS heads
    gemm_kernel<<<dim3(128 / 64, 64), blk, 0, stream>>>(FI, isp_w, isp_b, ISP, BSZ, 128, 128, 0);
    gemm_kernel<<<dim3(128 / 64, 64), blk, 0, stream>>>(FI, ish_w, ish_b, ISH, BSZ, 128, 128, 0);
    gemm_kernel<<<dim3(128 / 64, 64), blk, 0, stream>>>(FT, tsh_w, tsh_b, TSH, BSZ, 128, 128, 0);
    gemm_kernel<<<dim3(128 / 64, 64), blk, 0, stream>>>(FT, tsp_w, tsp_b, TSP, BSZ, 128, 128, 0);
    // normalize
    rownorm_kernel<<<16, 256, 0, stream>>>(FI, FIN);
    rownorm_kernel<<<16, 256, 0, stream>>>(FT, FTN);
    rownorm_kernel<<<16, 256, 0, stream>>>(ISH, ISHN);
    rownorm_kernel<<<16, 256, 0, stream>>>(TSH, TSHN);
    // clip losses
    clip_tile_kernel<<<dim3(64, 64), blk, 0, stream>>>(FIN, FTN, y, scale1, ST1);
    clip_finalize_kernel<<<16, 256, 0, stream>>>(ST1, y, scale1, SCAL, &SCAL[1]);
    clip_tile_kernel<<<dim3(64, 64), blk, 0, stream>>>(ISHN, TSHN, y, scale2, ST2);
    clip_finalize_kernel<<<16, 256, 0, stream>>>(ST2, y, scale2, SCAL, &SCAL[2]);
    // separate loss via Gram trick
    gram_kernel<<<dim3(8, 8, 16), blk, 0, stream>>>(ISP, GA);
    gram_kernel<<<dim3(8, 8, 16), blk, 0, stream>>>(ISH, GB);
    gram_kernel<<<dim3(8, 8, 16), blk, 0, stream>>>(TSP, GC);
    gram_kernel<<<dim3(8, 8, 16), blk, 0, stream>>>(TSH, GD);
    frob_dot_kernel<<<16, 256, 0, stream>>>(GA, GB, &SCAL[3]);
    frob_dot_kernel<<<16, 256, 0, stream>>>(GC, GD, &SCAL[4]);
    // scalar heads (output order: loss, i_sp_out, i_sh_out, t_sp_out, t_sh_out)
    head_kernel<<<16, 256, 0, stream>>>(ISP, c1_w, c1_b, out + 1);
    head_kernel<<<16, 256, 0, stream>>>(ISH, c2_w, c2_b, out + 1 + BSZ);
    head_kernel<<<16, 256, 0, stream>>>(TSP, c4_w, c4_b, out + 1 + 2 * BSZ);
    head_kernel<<<16, 256, 0, stream>>>(TSH, c3_w, c3_b, out + 1 + 3 * BSZ);
    // final combine
    final_kernel<<<1, 1, 0, stream>>>(SCAL, out);
}

// Round 2
// 778.757 us; speedup vs baseline: 1.6218x; 1.6218x over previous
//
#include <hip/hip_runtime.h>
#include <math.h>

#define BSZ 4096

typedef __attribute__((ext_vector_type(8))) short bf16x8;
typedef __attribute__((ext_vector_type(4))) float f32x4;

__device__ __forceinline__ unsigned short f2b(float f) {
    unsigned u = __float_as_uint(f);
    u = u + 0x7fffu + ((u >> 16) & 1u);
    return (unsigned short)(u >> 16);
}
__device__ __forceinline__ float b2f(unsigned short s) {
    return __uint_as_float(((unsigned)s) << 16);
}

// ---------------------------------------------------------------------------
// fp32 -> bf16 cast, 4 elems/thread (n multiple of 4)
// ---------------------------------------------------------------------------
__global__ void cast_kernel(const float* __restrict__ x, unsigned short* __restrict__ o, int n) {
    int i = (blockIdx.x * 256 + threadIdx.x) * 4;
    if (i >= n) return;
    float4 v = *(const float4*)(x + i);
    ushort4 r;
    r.x = f2b(v.x); r.y = f2b(v.y); r.z = f2b(v.z); r.w = f2b(v.w);
    *(ushort4*)(o + i) = r;
}

// Combined weight cast into one packed bf16 buffer (compile-time offsets).
__global__ void cast_w_kernel(const float* __restrict__ l1, const float* __restrict__ l2,
                              const float* __restrict__ l3, const float* __restrict__ tl2,
                              const float* __restrict__ isp, const float* __restrict__ ish,
                              const float* __restrict__ tsh, const float* __restrict__ tsp,
                              unsigned short* __restrict__ o) {
    int i = (blockIdx.x * 256 + threadIdx.x) * 4;
    if (i >= 1294336) return;
    const float* src; int off;
    if (i < 1048576)      { src = l1;  off = 0; }
    else if (i < 1179648) { src = l2;  off = 1048576; }
    else if (i < 1212416) { src = l3;  off = 1179648; }
    else if (i < 1228800) { src = tl2; off = 1212416; }
    else if (i < 1245184) { src = isp; off = 1228800; }
    else if (i < 1261568) { src = ish; off = 1245184; }
    else if (i < 1277952) { src = tsh; off = 1261568; }
    else                  { src = tsp; off = 1277952; }
    float4 v = *(const float4*)(src + (i - off));
    ushort4 r;
    r.x = f2b(v.x); r.y = f2b(v.y); r.z = f2b(v.z); r.w = f2b(v.w);
    *(ushort4*)(o + i) = r;
}

// ---------------------------------------------------------------------------
// SIMT GEMM (only for tl1, K=49), bf16 output. A:[M,K] f32, W:[N,K] f32.
// ---------------------------------------------------------------------------
__global__ void gemm_small(const float* __restrict__ A, const float* __restrict__ W,
                           const float* __restrict__ bias, unsigned short* __restrict__ C,
                           int M, int N, int K, int relu) {
    __shared__ float As[16][65];
    __shared__ float Ws[16][65];
    const int tx = threadIdx.x, ty = threadIdx.y;
    const int tid = ty * 16 + tx;
    const int m0 = blockIdx.y * 64, n0 = blockIdx.x * 64;
    float acc[4][4] = {};
    const int lrow = tid >> 2;
    const int lkb = (tid & 3) * 4;
    for (int k0 = 0; k0 < K; k0 += 16) {
#pragma unroll
        for (int u = 0; u < 4; ++u) {
            int k = k0 + lkb + u;
            As[lkb + u][lrow] = (k < K) ? A[(size_t)(m0 + lrow) * K + k] : 0.0f;
            Ws[lkb + u][lrow] = (k < K) ? W[(size_t)(n0 + lrow) * K + k] : 0.0f;
        }
        __syncthreads();
#pragma unroll
        for (int kk = 0; kk < 16; ++kk) {
            float av[4], bv[4];
#pragma unroll
            for (int i = 0; i < 4; ++i) av[i] = As[kk][ty * 4 + i];
#pragma unroll
            for (int j = 0; j < 4; ++j) bv[j] = Ws[kk][tx * 4 + j];
#pragma unroll
            for (int i = 0; i < 4; ++i)
#pragma unroll
                for (int j = 0; j < 4; ++j) acc[i][j] += av[i] * bv[j];
        }
        __syncthreads();
    }
#pragma unroll
    for (int i = 0; i < 4; ++i)
#pragma unroll
        for (int j = 0; j < 4; ++j) {
            int n = n0 + tx * 4 + j;
            float v = acc[i][j] + bias[n];
            if (relu) v = fmaxf(v, 0.0f);
            C[(size_t)(m0 + ty * 4 + i) * N + n] = f2b(v);
        }
}

// ---------------------------------------------------------------------------
// MFMA GEMM body: C = act(A @ W^T + bias). A:[M,K] bf16, W:[N,K] bf16.
// Tile 128x128, 4 waves (2x2 of 64x64), BK=64, 16x16x32 bf16 MFMA.
// LDS XOR-swizzle: LDS[row][cbp] holds global col-block (cbp ^ (row&7)).
// ---------------------------------------------------------------------------
__device__ __forceinline__ void gemm_body(const unsigned short* __restrict__ A,
                                          const unsigned short* __restrict__ W,
                                          const float* __restrict__ bias,
                                          unsigned short* __restrict__ Cb,
                                          float* __restrict__ Cf,
                                          int N, int K, int relu, int bx, int by,
                                          short* As, short* Bs) {
    const int tid = threadIdx.x;
    const int w = tid >> 6, lane = tid & 63, quad = lane >> 4, l15 = lane & 15;
    const int m0 = by * 128, n0 = bx * 128;
    const int rw = (w >> 1) * 64, cw = (w & 1) * 64;
    f32x4 acc[4][4];
#pragma unroll
    for (int i = 0; i < 4; ++i)
#pragma unroll
        for (int j = 0; j < 4; ++j) acc[i][j] = (f32x4){0.f, 0.f, 0.f, 0.f};

    for (int k0 = 0; k0 < K; k0 += 64) {
#pragma unroll
        for (int r = 0; r < 4; ++r) {
            int idx = r * 256 + tid;
            int row = idx >> 3, cbp = idx & 7;
            int col = ((cbp ^ (row & 7)) << 3);
            *(bf16x8*)&As[row * 64 + cbp * 8] = *(const bf16x8*)&A[(size_t)(m0 + row) * K + k0 + col];
            *(bf16x8*)&Bs[row * 64 + cbp * 8] = *(const bf16x8*)&W[(size_t)(n0 + row) * K + k0 + col];
        }
        __syncthreads();
#pragma unroll
        for (int kb = 0; kb < 2; ++kb) {
            bf16x8 af[4], bfr[4];
            int cb = kb * 4 + quad;
#pragma unroll
            for (int i = 0; i < 4; ++i) {
                int row = rw + i * 16 + l15;
                af[i] = *(const bf16x8*)&As[row * 64 + ((cb ^ (row & 7)) << 3)];
            }
#pragma unroll
            for (int j = 0; j < 4; ++j) {
                int row = cw + j * 16 + l15;
                bfr[j] = *(const bf16x8*)&Bs[row * 64 + ((cb ^ (row & 7)) << 3)];
            }
#pragma unroll
            for (int i = 0; i < 4; ++i)
#pragma unroll
                for (int j = 0; j < 4; ++j)
                    acc[i][j] = __builtin_amdgcn_mfma_f32_16x16x32_bf16(af[i], bfr[j], acc[i][j], 0, 0, 0);
        }
        __syncthreads();
    }
    // epilogue: C/D layout col=lane&15 (n), row=quad*4+reg (m)
#pragma unroll
    for (int j = 0; j < 4; ++j) {
        int n = n0 + cw + j * 16 + l15;
        float bv = bias[n];
#pragma unroll
        for (int i = 0; i < 4; ++i) {
#pragma unroll
            for (int r = 0; r < 4; ++r) {
                int m = m0 + rw + i * 16 + quad * 4 + r;
                float v = acc[i][j][r] + bv;
                if (relu) v = fmaxf(v, 0.f);
                if (Cb) Cb[(size_t)m * N + n] = f2b(v);
                if (Cf) Cf[(size_t)m * N + n] = v;
            }
        }
    }
}

__global__ __launch_bounds__(256) void mfma_gemm(const unsigned short* __restrict__ A,
                                                 const unsigned short* __restrict__ W,
                                                 const float* __restrict__ bias,
                                                 unsigned short* __restrict__ Cb,
                                                 float* __restrict__ Cf, int N, int K, int relu) {
    __shared__ alignas(16) short As[128 * 64];
    __shared__ alignas(16) short Bs[128 * 64];
    gemm_body(A, W, bias, Cb, Cf, N, K, relu, blockIdx.x, blockIdx.y, As, Bs);
}

// Batched SS heads: z selects (input, weight, bias, out). N=K=128, fp32 out.
__global__ __launch_bounds__(256) void mfma_heads(const unsigned short* __restrict__ FIb,
                                                  const unsigned short* __restrict__ FTb,
                                                  const unsigned short* __restrict__ Wisp,
                                                  const unsigned short* __restrict__ Wish,
                                                  const unsigned short* __restrict__ Wtsh,
                                                  const unsigned short* __restrict__ Wtsp,
                                                  const float* __restrict__ bisp, const float* __restrict__ bish,
                                                  const float* __restrict__ btsh, const float* __restrict__ btsp,
                                                  float* __restrict__ ISP, float* __restrict__ ISH,
                                                  float* __restrict__ TSH, float* __restrict__ TSP) {
    __shared__ alignas(16) short As[128 * 64];
    __shared__ alignas(16) short Bs[128 * 64];
    int z = blockIdx.z;
    const unsigned short* A = (z < 2) ? FIb : FTb;
    const unsigned short* W = z == 0 ? Wisp : z == 1 ? Wish : z == 2 ? Wtsh : Wtsp;
    const float* b = z == 0 ? bisp : z == 1 ? bish : z == 2 ? btsh : btsp;
    float* C = z == 0 ? ISP : z == 1 ? ISH : z == 2 ? TSH : TSP;
    gemm_body(A, W, b, nullptr, C, 128, 128, 0, 0, blockIdx.y, As, Bs);
}

// ---------------------------------------------------------------------------
// Row-normalize (z-batched, 4 tensors): out bf16. z<2 inputs bf16, else fp32.
// ---------------------------------------------------------------------------
__global__ void rownorm4(const unsigned short* __restrict__ fi, const unsigned short* __restrict__ ft,
                         const float* __restrict__ ish, const float* __restrict__ tsh,
                         unsigned short* __restrict__ fin, unsigned short* __restrict__ ftn,
                         unsigned short* __restrict__ ishn, unsigned short* __restrict__ tshn) {
    int z = blockIdx.y;
    int m = blockIdx.x * 256 + threadIdx.x;
    const unsigned short* sb = (z == 0) ? fi : ft;
    const float* sf = (z == 2) ? ish : tsh;
    unsigned short* dst = z == 0 ? fin : z == 1 ? ftn : z == 2 ? ishn : tshn;
    float ss = 0.f;
    if (z < 2) {
        for (int u = 0; u < 128; u += 8) {
            bf16x8 v = *(const bf16x8*)&sb[(size_t)m * 128 + u];
#pragma unroll
            for (int e = 0; e < 8; ++e) { float f = b2f((unsigned short)v[e]); ss += f * f; }
        }
    } else {
        for (int u = 0; u < 128; u += 4) {
            float4 v = *(const float4*)&sf[(size_t)m * 128 + u];
            ss += v.x * v.x + v.y * v.y + v.z * v.z + v.w * v.w;
        }
    }
    float inv = 1.f / fmaxf(sqrtf(ss), 1e-12f);
    if (z < 2) {
        for (int u = 0; u < 128; u += 8) {
            bf16x8 v = *(const bf16x8*)&sb[(size_t)m * 128 + u];
            ushort4 o0, o1;
            o0.x = f2b(b2f((unsigned short)v[0]) * inv); o0.y = f2b(b2f((unsigned short)v[1]) * inv);
            o0.z = f2b(b2f((unsigned short)v[2]) * inv); o0.w = f2b(b2f((unsigned short)v[3]) * inv);
            o1.x = f2b(b2f((unsigned short)v[4]) * inv); o1.y = f2b(b2f((unsigned short)v[5]) * inv);
            o1.z = f2b(b2f((unsigned short)v[6]) * inv); o1.w = f2b(b2f((unsigned short)v[7]) * inv);
            *(ushort4*)&dst[(size_t)m * 128 + u] = o0;
            *(ushort4*)&dst[(size_t)m * 128 + u + 4] = o1;
        }
    } else {
        for (int u = 0; u < 128; u += 4) {
            float4 v = *(const float4*)&sf[(size_t)m * 128 + u];
            ushort4 o;
            o.x = f2b(v.x * inv); o.y = f2b(v.y * inv); o.z = f2b(v.z * inv); o.w = f2b(v.w * inv);
            *(ushort4*)&dst[(size_t)m * 128 + u] = o;
        }
    }
}

// ---------------------------------------------------------------------------
// Count y==0 -> scal[0]
// ---------------------------------------------------------------------------
__global__ void county_kernel(const int* __restrict__ y, float* __restrict__ scal) {
    __shared__ int red[256];
    int t = threadIdx.x;
    int c = 0;
    for (int i = t; i < BSZ; i += 256) c += (y[i] == 0) ? 1 : 0;
    red[t] = c;
    __syncthreads();
    for (int s = 128; s > 0; s >>= 1) {
        if (t < s) red[t] += red[t + s];
        __syncthreads();
    }
    if (t == 0) scal[0] = (float)red[0];
}

// ---------------------------------------------------------------------------
// MFMA CLIP tile: S = In @ Tn^T, 128x128 tile/block, K=128 staged once.
// Stats into st: [0]=rowZ(sum e^L) [1]=rowF(sum e^L*L) [2]=rowW(same e^L)
//                [3]=colZ(sum e^S) [4]=colE(sum e^S*S) [5]=colW(same e^S)
//                st[6*BSZ+{0..3}] = T[yr][yc] = sum S by class pair.
// ---------------------------------------------------------------------------
__global__ __launch_bounds__(256) void clip_mfma(const unsigned short* __restrict__ In,
                                                 const unsigned short* __restrict__ Tn,
                                                 const int* __restrict__ y,
                                                 const float* __restrict__ scale_log,
                                                 float* __restrict__ st) {
    __shared__ alignas(16) short As[128 * 128];
    __shared__ alignas(16) short Bs[128 * 128];
    const int tid = threadIdx.x;
    const int w = tid >> 6, lane = tid & 63, quad = lane >> 4, l15 = lane & 15;
    const int r0 = blockIdx.y * 128, c0 = blockIdx.x * 128;
    const int rw = (w >> 1) * 64, cw = (w & 1) * 64;
#pragma unroll
    for (int r = 0; r < 8; ++r) {
        int idx = r * 256 + tid;
        int row = idx >> 4, cbp = idx & 15;
        int col = ((cbp ^ (row & 7)) << 3);
        *(bf16x8*)&As[row * 128 + cbp * 8] = *(const bf16x8*)&In[(size_t)(r0 + row) * 128 + col];
        *(bf16x8*)&Bs[row * 128 + cbp * 8] = *(const bf16x8*)&Tn[(size_t)(c0 + row) * 128 + col];
    }
    __syncthreads();
    f32x4 acc[4][4];
#pragma unroll
    for (int i = 0; i < 4; ++i)
#pragma unroll
        for (int j = 0; j < 4; ++j) acc[i][j] = (f32x4){0.f, 0.f, 0.f, 0.f};
#pragma unroll
    for (int kb = 0; kb < 4; ++kb) {
        bf16x8 af[4], bfr[4];
        int cb = kb * 4 + quad;
#pragma unroll
        for (int i = 0; i < 4; ++i) {
            int row = rw + i * 16 + l15;
            af[i] = *(const bf16x8*)&As[row * 128 + ((cb ^ (row & 7)) << 3)];
        }
#pragma unroll
        for (int j = 0; j < 4; ++j) {
            int row = cw + j * 16 + l15;
            bfr[j] = *(const bf16x8*)&Bs[row * 128 + ((cb ^ (row & 7)) << 3)];
        }
#pragma unroll
        for (int i = 0; i < 4; ++i)
#pragma unroll
            for (int j = 0; j < 4; ++j)
                acc[i][j] = __builtin_amdgcn_mfma_f32_16x16x32_bf16(af[i], bfr[j], acc[i][j], 0, 0, 0);
    }

    const float s = expf(scale_log[0]);
    int yrow[4][4]; float mrow[4][4];
    int ycol[4];    float mcol[4];
#pragma unroll
    for (int i = 0; i < 4; ++i)
#pragma unroll
        for (int r = 0; r < 4; ++r) {
            int yy = y[r0 + rw + i * 16 + quad * 4 + r];
            yrow[i][r] = yy; mrow[i][r] = (yy == 0) ? 1.f : 0.f;
        }
#pragma unroll
    for (int j = 0; j < 4; ++j) {
        int yy = y[c0 + cw + j * 16 + l15];
        ycol[j] = yy; mcol[j] = (yy == 0) ? 1.f : 0.f;
    }
    float rZ[4][4] = {}, rF[4][4] = {}, rW[4][4] = {};
    float cZ[4] = {}, cE[4] = {}, cW[4] = {};
    float aAll = 0.f, aC0 = 0.f, aR0 = 0.f, aRC = 0.f;
#pragma unroll
    for (int i = 0; i < 4; ++i)
#pragma unroll
        for (int r = 0; r < 4; ++r) {
            float mr = mrow[i][r];
            int yr = yrow[i][r];
#pragma unroll
            for (int j = 0; j < 4; ++j) {
                float S = acc[i][j][r];
                float L = s * S;
                float e1 = __expf(L);
                float e2 = __expf(S);
                float msk = (yr == ycol[j]) ? 1.f : 0.f;
                rZ[i][r] += e1; rF[i][r] += e1 * L; rW[i][r] += e1 * msk;
                cZ[j] += e2;    cE[j] += e2 * S;    cW[j] += e2 * msk;
                float tmp = S * mcol[j];
                aAll += S; aC0 += tmp; aR0 += S * mr; aRC += tmp * mr;
            }
        }
    // row reduce across the 16 lanes of each quad; guarded write (exec-masked)
#pragma unroll
    for (int i = 0; i < 4; ++i)
#pragma unroll
        for (int r = 0; r < 4; ++r) {
#pragma unroll
            for (int m = 1; m < 16; m <<= 1) {
                rZ[i][r] += __shfl_xor(rZ[i][r], m);
                rF[i][r] += __shfl_xor(rF[i][r], m);
                rW[i][r] += __shfl_xor(rW[i][r], m);
            }
            if (l15 == (i * 4 + r)) {
                int grow = r0 + rw + i * 16 + quad * 4 + r;
                atomicAdd(&st[grow], rZ[i][r]);
                atomicAdd(&st[BSZ + grow], rF[i][r]);
                atomicAdd(&st[2 * BSZ + grow], rW[i][r]);
            }
        }
    // col reduce across quads
#pragma unroll
    for (int j = 0; j < 4; ++j) {
        cZ[j] += __shfl_xor(cZ[j], 16); cZ[j] += __shfl_xor(cZ[j], 32);
        cE[j] += __shfl_xor(cE[j], 16); cE[j] += __shfl_xor(cE[j], 32);
        cW[j] += __shfl_xor(cW[j], 16); cW[j] += __shfl_xor(cW[j], 32);
        if (quad == 0) {
            int gcol = c0 + cw + j * 16 + l15;
            atomicAdd(&st[3 * BSZ + gcol], cZ[j]);
            atomicAdd(&st[4 * BSZ + gcol], cE[j]);
            atomicAdd(&st[5 * BSZ + gcol], cW[j]);
        }
    }
    // T scalars
#pragma unroll
    for (int m = 1; m < 64; m <<= 1) {
        aAll += __shfl_xor(aAll, m); aC0 += __shfl_xor(aC0, m);
        aR0 += __shfl_xor(aR0, m);   aRC += __shfl_xor(aRC, m);
    }
    if (lane == 0) {
        float T00 = aRC, T01 = aR0 - aRC, T10 = aC0 - aRC, T11 = aAll - aR0 - aC0 + aRC;
        atomicAdd(&st[6 * BSZ + 0], T00);
        atomicAdd(&st[6 * BSZ + 1], T01);
        atomicAdd(&st[6 * BSZ + 2], T10);
        atomicAdd(&st[6 * BSZ + 3], T11);
    }
}

// ---------------------------------------------------------------------------
// CLIP finalize (logZ cancels between the KL pair):
// per-k: Qlq + F/Z - lq_d - (lq_s-lq_d)*W/Z  (both directions); S-terms from T.
// ---------------------------------------------------------------------------
__global__ void clip_finalize(const float* __restrict__ st, const int* __restrict__ y,
                              const float* __restrict__ scale_log, const float* __restrict__ scal,
                              float* __restrict__ loss_slot) {
    __shared__ float red[256];
    int k = blockIdx.x * 256 + threadIdx.x;
    const float Bf = (float)BSZ;
    const float n0 = scal[0];
    int yk = y[k];
    float n = (yk == 0) ? n0 : (Bf - n0);
    float a = 1.0f / n;
    float ea = expf(a);
    float denom = n * ea + (Bf - n);
    float q_s = ea / denom, q_d = 1.0f / denom;
    float ld = logf(denom);
    float lq_s = a - ld, lq_d = -ld;
    float Qlq = n * q_s * lq_s + (Bf - n) * q_d * lq_d;

    float Z1 = st[k], F1 = st[BSZ + k], W1 = st[2 * BSZ + k];
    float term_r = Qlq + F1 / Z1 - lq_d - (lq_s - lq_d) * (W1 / Z1);
    float Z2 = st[3 * BSZ + k], E2 = st[4 * BSZ + k], W2 = st[5 * BSZ + k];
    float term_c = Qlq + E2 / Z2 - lq_d - (lq_s - lq_d) * (W2 / Z2);
    float v = (term_r + term_c) / (4.0f * Bf);
    int t = threadIdx.x;
    red[t] = v;
    __syncthreads();
    for (int ss2 = 128; ss2 > 0; ss2 >>= 1) {
        if (t < ss2) red[t] += red[t + ss2];
        __syncthreads();
    }
    if (t == 0) atomicAdd(loss_slot, red[0]);
    if (blockIdx.x == 0 && threadIdx.x == 0) {
        const float s = expf(scale_log[0]);
        float n1 = Bf - n0;
        float a0 = 1.f / n0, a1 = 1.f / n1;
        float e0 = expf(a0), e1 = expf(a1);
        float d0 = n0 * e0 + (Bf - n0), d1 = n1 * e1 + (Bf - n1);
        float qs0 = e0 / d0, qd0 = 1.f / d0, qs1 = e1 / d1, qd1 = 1.f / d1;
        float T00 = st[6 * BSZ + 0], T01 = st[6 * BSZ + 1];
        float T10 = st[6 * BSZ + 2], T11 = st[6 * BSZ + 3];
        float QS1 = qd0 * (T00 + T01) + (qs0 - qd0) * T00 + qd1 * (T10 + T11) + (qs1 - qd1) * T11;
        float QS2 = qd0 * (T00 + T10) + (qs0 - qd0) * T00 + qd1 * (T01 + T11) + (qs1 - qd1) * T11;
        atomicAdd(loss_slot, (-s * QS1 - QS2) / (4.0f * Bf));
    }
}

// ---------------------------------------------------------------------------
// Gram (z-batched over 4 matrices + 16 row-chunks)
// ---------------------------------------------------------------------------
__global__ void gram4(const float* __restrict__ isp, const float* __restrict__ ish,
                      const float* __restrict__ tsp, const float* __restrict__ tsh,
                      float* __restrict__ G) {
    int mat = blockIdx.z >> 4, chunk = blockIdx.z & 15;
    const float* A = mat == 0 ? isp : mat == 1 ? ish : mat == 2 ? tsp : tsh;
    float* Gm = G + mat * 16384;
    int a = blockIdx.y * 16 + threadIdx.y;
    int b = blockIdx.x * 16 + threadIdx.x;
    int m0 = chunk * 256;
    float acc = 0.0f;
    for (int m = m0; m < m0 + 256; ++m)
        acc += A[(size_t)m * 128 + a] * A[(size_t)m * 128 + b];
    atomicAdd(&Gm[a * 128 + b], acc);
}

__global__ void frob2(const float* __restrict__ G, float* __restrict__ scal) {
    __shared__ float red[256];
    int z = blockIdx.y;
    const float* GA = G + (z ? 2 : 0) * 16384;
    const float* GB = G + (z ? 3 : 1) * 16384;
    int t = threadIdx.x;
    float acc = 0.0f;
    for (int u = blockIdx.x * 256 + t; u < 16384; u += 16 * 256)
        acc += GA[u] * GB[u];
    red[t] = acc;
    __syncthreads();
    for (int s = 128; s > 0; s >>= 1) {
        if (t < s) red[t] += red[t + s];
        __syncthreads();
    }
    if (t == 0) atomicAdd(&scal[3 + z], red[0]);
}

// ---------------------------------------------------------------------------
// Scalar heads (z-batched): out[1 + z*BSZ + m] = dot(X[m], w) + b
// z: 0=(ISP,c1) 1=(ISH,c2) 2=(TSP,c4) 3=(TSH,c3)
// ---------------------------------------------------------------------------
__global__ void head4(const float* __restrict__ isp, const float* __restrict__ ish,
                      const float* __restrict__ tsp, const float* __restrict__ tsh,
                      const float* __restrict__ c1w, const float* __restrict__ c2w,
                      const float* __restrict__ c4w, const float* __restrict__ c3w,
                      const float* __restrict__ c1b, const float* __restrict__ c2b,
                      const float* __restrict__ c4b, const float* __restrict__ c3b,
                      float* __restrict__ out) {
    int z = blockIdx.y;
    const float* X = z == 0 ? isp : z == 1 ? ish : z == 2 ? tsp : tsh;
    const float* w = z == 0 ? c1w : z == 1 ? c2w : z == 2 ? c4w : c3w;
    const float* b = z == 0 ? c1b : z == 1 ? c2b : z == 2 ? c4b : c3b;
    int m = blockIdx.x * 256 + threadIdx.x;
    const float4* xp = (const float4*)(X + (size_t)m * 128);
    const float4* wp = (const float4*)w;
    float acc = 0.0f;
#pragma unroll
    for (int u = 0; u < 32; ++u) {
        float4 av = xp[u], cv = wp[u];
        acc += av.x * cv.x + av.y * cv.y + av.z * cv.z + av.w * cv.w;
    }
    out[1 + (size_t)z * BSZ + m] = acc + b[0];
}

__global__ void final_kernel(const float* __restrict__ scal, float* __restrict__ out) {
    float loss1 = scal[1];
    float loss_sh = scal[2];
    float ss_i = scal[3];
    float ss_t = scal[4];
    float loss_sp = 0.5f * (sqrtf(ss_t) + sqrtf(ss_i));
    out[0] = (loss_sp + loss_sh + loss1) / 3.0f;
}

// ---------------------------------------------------------------------------
extern "C" void kernel_launch(void* const* d_in, const int* in_sizes, int n_in,
                              void* d_out, int out_size, void* d_ws, size_t ws_size,
                              hipStream_t stream) {
    const float* i_in  = (const float*)d_in[0];
    const float* t_in  = (const float*)d_in[1];
    const int*   y     = (const int*)d_in[2];
    const float* l1_w  = (const float*)d_in[3];
    const float* l1_b  = (const float*)d_in[4];
    const float* l2_w  = (const float*)d_in[5];
    const float* l2_b  = (const float*)d_in[6];
    const float* l3_w  = (const float*)d_in[7];
    const float* l3_b  = (const float*)d_in[8];
    const float* tl1_w = (const float*)d_in[9];
    const float* tl1_b = (const float*)d_in[10];
    const float* tl2_w = (const float*)d_in[11];
    const float* tl2_b = (const float*)d_in[12];
    const float* isp_w = (const float*)d_in[13];
    const float* isp_b = (const float*)d_in[14];
    const float* ish_w = (const float*)d_in[15];
    const float* ish_b = (const float*)d_in[16];
    const float* tsh_w = (const float*)d_in[17];
    const float* tsh_b = (const float*)d_in[18];
    const float* tsp_w = (const float*)d_in[19];
    const float* tsp_b = (const float*)d_in[20];
    const float* c1_w  = (const float*)d_in[21];
    const float* c1_b  = (const float*)d_in[22];
    const float* c2_w  = (const float*)d_in[23];
    const float* c2_b  = (const float*)d_in[24];
    const float* c3_w  = (const float*)d_in[25];
    const float* c3_b  = (const float*)d_in[26];
    const float* c4_w  = (const float*)d_in[27];
    const float* c4_b  = (const float*)d_in[28];
    const float* scale1 = (const float*)d_in[29];
    const float* scale2 = (const float*)d_in[30];

    float* ws = (float*)d_ws;
    // zeroed fp32 region
    float* SCAL = ws;                       // 64
    float* ST1  = ws + 64;                  // 24640 (6*4096 + 16, padded)
    float* ST2  = ST1 + 24640;              // 24640
    float* GMS  = ST2 + 24640;              // 4*16384
    // fp32 work buffers
    float* ISP  = GMS + 4 * 16384;
    float* ISH  = ISP + (size_t)BSZ * 128;
    float* TSP  = ISH + (size_t)BSZ * 128;
    float* TSH  = TSP + (size_t)BSZ * 128;
    // bf16 buffers
    unsigned short* IB   = (unsigned short*)(TSH + (size_t)BSZ * 128);
    unsigned short* WB   = IB + (size_t)BSZ * 2048;      // 1294336
    unsigned short* FI1B = WB + 1294336;                 // 4096*512
    unsigned short* FI2B = FI1B + (size_t)BSZ * 512;     // 4096*256
    unsigned short* FIB  = FI2B + (size_t)BSZ * 256;     // 4096*128
    unsigned short* FT1B = FIB + (size_t)BSZ * 128;
    unsigned short* FTB  = FT1B + (size_t)BSZ * 128;
    unsigned short* FINB = FTB + (size_t)BSZ * 128;
    unsigned short* FTNB = FINB + (size_t)BSZ * 128;
    unsigned short* ISHN = FTNB + (size_t)BSZ * 128;
    unsigned short* TSHN = ISHN + (size_t)BSZ * 128;

    float* out = (float*)d_out;

    hipMemsetAsync(d_ws, 0, 114880 * sizeof(float), stream);
    county_kernel<<<1, 256, 0, stream>>>(y, SCAL);
    cast_kernel<<<8192, 256, 0, stream>>>(i_in, IB, BSZ * 2048);
    cast_w_kernel<<<1264, 256, 0, stream>>>(l1_w, l2_w, l3_w, tl2_w, isp_w, ish_w, tsh_w, tsp_w, WB);
    gemm_small<<<dim3(2, 64), dim3(16, 16), 0, stream>>>(t_in, tl1_w, tl1_b, FT1B, BSZ, 128, 49, 1);

    mfma_gemm<<<dim3(4, 32), 256, 0, stream>>>(IB, WB, l1_b, FI1B, nullptr, 512, 2048, 1);
    mfma_gemm<<<dim3(2, 32), 256, 0, stream>>>(FI1B, WB + 1048576, l2_b, FI2B, nullptr, 256, 512, 1);
    mfma_gemm<<<dim3(1, 32), 256, 0, stream>>>(FI2B, WB + 1179648, l3_b, FIB, nullptr, 128, 256, 0);
    mfma_gemm<<<dim3(1, 32), 256, 0, stream>>>(FT1B, WB + 1212416, tl2_b, FTB, nullptr, 128, 128, 0);
    mfma_heads<<<dim3(1, 32, 4), 256, 0, stream>>>(FIB, FTB, WB + 1228800, WB + 1245184, WB + 1261568,
                                                   WB + 1277952, isp_b, ish_b, tsh_b, tsp_b,
                                                   ISP, ISH, TSH, TSP);
    rownorm4<<<dim3(16, 4), 256, 0, stream>>>(FIB, FTB, ISH, TSH, FINB, FTNB, ISHN, TSHN);

    clip_mfma<<<dim3(32, 32), 256, 0, stream>>>(FINB, FTNB, y, scale1, ST1);
    clip_mfma<<<dim3(32, 32), 256, 0, stream>>>(ISHN, TSHN, y, scale2, ST2);
    clip_finalize<<<16, 256, 0, stream>>>(ST1, y, scale1, SCAL, &SCAL[1]);
    clip_finalize<<<16, 256, 0, stream>>>(ST2, y, scale2, SCAL, &SCAL[2]);

    gram4<<<dim3(8, 8, 64), dim3(16, 16), 0, stream>>>(ISP, ISH, TSP, TSH, GMS);
    frob2<<<dim3(16, 2), 256, 0, stream>>>(GMS, SCAL);
    head4<<<dim3(16, 4), 256, 0, stream>>>(ISP, ISH, TSP, TSH, c1_w, c2_w, c4_w, c3_w,
                                           c1_b, c2_b, c4_b, c3_b, out);
    final_kernel<<<1, 1, 0, stream>>>(SCAL, out);
}

// Round 3
// 387.826 us; speedup vs baseline: 3.2566x; 2.0080x over previous
//
#include <hip/hip_runtime.h>
#include <math.h>

#define BSZ 4096

typedef __attribute__((ext_vector_type(8))) short bf16x8;
typedef __attribute__((ext_vector_type(4))) float f32x4;

// ST layout (floats): rowZ@0, rowF@262144, rowW@524288 (each [64 part][4096 row])
//                     colZ@786432, colE@1048576, colW@1310720
//                     Tpart@1572864 ([4096 waves][4])
#define ST_ROW 0
#define ST_COL 786432
#define ST_T   1572864
#define ST_FLOATS 1589248

__device__ __forceinline__ unsigned short f2b(float f) {
    unsigned u = __float_as_uint(f);
    u = u + 0x7fffu + ((u >> 16) & 1u);
    return (unsigned short)(u >> 16);
}
__device__ __forceinline__ float b2f(unsigned short s) {
    return __uint_as_float(((unsigned)s) << 16);
}

// ---------------------------------------------------------------------------
// fp32 -> bf16 cast, 4 elems/thread (n multiple of 4)
// ---------------------------------------------------------------------------
__global__ void cast_kernel(const float* __restrict__ x, unsigned short* __restrict__ o, int n) {
    int i = (blockIdx.x * 256 + threadIdx.x) * 4;
    if (i >= n) return;
    float4 v = *(const float4*)(x + i);
    ushort4 r;
    r.x = f2b(v.x); r.y = f2b(v.y); r.z = f2b(v.z); r.w = f2b(v.w);
    *(ushort4*)(o + i) = r;
}

// Combined weight cast into one packed bf16 buffer (compile-time offsets).
__global__ void cast_w_kernel(const float* __restrict__ l1, const float* __restrict__ l2,
                              const float* __restrict__ l3, const float* __restrict__ tl2,
                              const float* __restrict__ isp, const float* __restrict__ ish,
                              const float* __restrict__ tsh, const float* __restrict__ tsp,
                              unsigned short* __restrict__ o) {
    int i = (blockIdx.x * 256 + threadIdx.x) * 4;
    if (i >= 1294336) return;
    const float* src; int off;
    if (i < 1048576)      { src = l1;  off = 0; }
    else if (i < 1179648) { src = l2;  off = 1048576; }
    else if (i < 1212416) { src = l3;  off = 1179648; }
    else if (i < 1228800) { src = tl2; off = 1212416; }
    else if (i < 1245184) { src = isp; off = 1228800; }
    else if (i < 1261568) { src = ish; off = 1245184; }
    else if (i < 1277952) { src = tsh; off = 1261568; }
    else                  { src = tsp; off = 1277952; }
    float4 v = *(const float4*)(src + (i - off));
    ushort4 r;
    r.x = f2b(v.x); r.y = f2b(v.y); r.z = f2b(v.z); r.w = f2b(v.w);
    *(ushort4*)(o + i) = r;
}

// ---------------------------------------------------------------------------
// SIMT GEMM (only for tl1, K=49), bf16 output. A:[M,K] f32, W:[N,K] f32.
// ---------------------------------------------------------------------------
__global__ void gemm_small(const float* __restrict__ A, const float* __restrict__ W,
                           const float* __restrict__ bias, unsigned short* __restrict__ C,
                           int M, int N, int K, int relu) {
    __shared__ float As[16][65];
    __shared__ float Ws[16][65];
    const int tx = threadIdx.x, ty = threadIdx.y;
    const int tid = ty * 16 + tx;
    const int m0 = blockIdx.y * 64, n0 = blockIdx.x * 64;
    float acc[4][4] = {};
    const int lrow = tid >> 2;
    const int lkb = (tid & 3) * 4;
    for (int k0 = 0; k0 < K; k0 += 16) {
#pragma unroll
        for (int u = 0; u < 4; ++u) {
            int k = k0 + lkb + u;
            As[lkb + u][lrow] = (k < K) ? A[(size_t)(m0 + lrow) * K + k] : 0.0f;
            Ws[lkb + u][lrow] = (k < K) ? W[(size_t)(n0 + lrow) * K + k] : 0.0f;
        }
        __syncthreads();
#pragma unroll
        for (int kk = 0; kk < 16; ++kk) {
            float av[4], bv[4];
#pragma unroll
            for (int i = 0; i < 4; ++i) av[i] = As[kk][ty * 4 + i];
#pragma unroll
            for (int j = 0; j < 4; ++j) bv[j] = Ws[kk][tx * 4 + j];
#pragma unroll
            for (int i = 0; i < 4; ++i)
#pragma unroll
                for (int j = 0; j < 4; ++j) acc[i][j] += av[i] * bv[j];
        }
        __syncthreads();
    }
#pragma unroll
    for (int i = 0; i < 4; ++i)
#pragma unroll
        for (int j = 0; j < 4; ++j) {
            int n = n0 + tx * 4 + j;
            float v = acc[i][j] + bias[n];
            if (relu) v = fmaxf(v, 0.0f);
            C[(size_t)(m0 + ty * 4 + i) * N + n] = f2b(v);
        }
}

// ---------------------------------------------------------------------------
// MFMA GEMM body: C = act(A @ W^T + bias). A:[M,K] bf16, W:[N,K] bf16.
// Tile 128x128, 4 waves (2x2 of 64x64), BK=64, 16x16x32 bf16 MFMA.
// LDS XOR-swizzle: LDS[row][cbp] holds global col-block (cbp ^ (row&7)).
// ---------------------------------------------------------------------------
__device__ __forceinline__ void gemm_body(const unsigned short* __restrict__ A,
                                          const unsigned short* __restrict__ W,
                                          const float* __restrict__ bias,
                                          unsigned short* __restrict__ Cb,
                                          float* __restrict__ Cf,
                                          int N, int K, int relu, int bx, int by,
                                          short* As, short* Bs) {
    const int tid = threadIdx.x;
    const int w = tid >> 6, lane = tid & 63, quad = lane >> 4, l15 = lane & 15;
    const int m0 = by * 128, n0 = bx * 128;
    const int rw = (w >> 1) * 64, cw = (w & 1) * 64;
    f32x4 acc[4][4];
#pragma unroll
    for (int i = 0; i < 4; ++i)
#pragma unroll
        for (int j = 0; j < 4; ++j) acc[i][j] = (f32x4){0.f, 0.f, 0.f, 0.f};

    for (int k0 = 0; k0 < K; k0 += 64) {
#pragma unroll
        for (int r = 0; r < 4; ++r) {
            int idx = r * 256 + tid;
            int row = idx >> 3, cbp = idx & 7;
            int col = ((cbp ^ (row & 7)) << 3);
            *(bf16x8*)&As[row * 64 + cbp * 8] = *(const bf16x8*)&A[(size_t)(m0 + row) * K + k0 + col];
            *(bf16x8*)&Bs[row * 64 + cbp * 8] = *(const bf16x8*)&W[(size_t)(n0 + row) * K + k0 + col];
        }
        __syncthreads();
#pragma unroll
        for (int kb = 0; kb < 2; ++kb) {
            bf16x8 af[4], bfr[4];
            int cb = kb * 4 + quad;
#pragma unroll
            for (int i = 0; i < 4; ++i) {
                int row = rw + i * 16 + l15;
                af[i] = *(const bf16x8*)&As[row * 64 + ((cb ^ (row & 7)) << 3)];
            }
#pragma unroll
            for (int j = 0; j < 4; ++j) {
                int row = cw + j * 16 + l15;
                bfr[j] = *(const bf16x8*)&Bs[row * 64 + ((cb ^ (row & 7)) << 3)];
            }
#pragma unroll
            for (int i = 0; i < 4; ++i)
#pragma unroll
                for (int j = 0; j < 4; ++j)
                    acc[i][j] = __builtin_amdgcn_mfma_f32_16x16x32_bf16(af[i], bfr[j], acc[i][j], 0, 0, 0);
        }
        __syncthreads();
    }
    // epilogue: C/D layout col=lane&15 (n), row=quad*4+reg (m)
#pragma unroll
    for (int j = 0; j < 4; ++j) {
        int n = n0 + cw + j * 16 + l15;
        float bv = bias[n];
#pragma unroll
        for (int i = 0; i < 4; ++i) {
#pragma unroll
            for (int r = 0; r < 4; ++r) {
                int m = m0 + rw + i * 16 + quad * 4 + r;
                float v = acc[i][j][r] + bv;
                if (relu) v = fmaxf(v, 0.f);
                if (Cb) Cb[(size_t)m * N + n] = f2b(v);
                if (Cf) Cf[(size_t)m * N + n] = v;
            }
        }
    }
}

__global__ __launch_bounds__(256) void mfma_gemm(const unsigned short* __restrict__ A,
                                                 const unsigned short* __restrict__ W,
                                                 const float* __restrict__ bias,
                                                 unsigned short* __restrict__ Cb,
                                                 float* __restrict__ Cf, int N, int K, int relu) {
    __shared__ alignas(16) short As[128 * 64];
    __shared__ alignas(16) short Bs[128 * 64];
    gemm_body(A, W, bias, Cb, Cf, N, K, relu, blockIdx.x, blockIdx.y, As, Bs);
}

// Batched SS heads: z selects (input, weight, bias, out). N=K=128, fp32 out.
__global__ __launch_bounds__(256) void mfma_heads(const unsigned short* __restrict__ FIb,
                                                  const unsigned short* __restrict__ FTb,
                                                  const unsigned short* __restrict__ Wisp,
                                                  const unsigned short* __restrict__ Wish,
                                                  const unsigned short* __restrict__ Wtsh,
                                                  const unsigned short* __restrict__ Wtsp,
                                                  const float* __restrict__ bisp, const float* __restrict__ bish,
                                                  const float* __restrict__ btsh, const float* __restrict__ btsp,
                                                  float* __restrict__ ISP, float* __restrict__ ISH,
                                                  float* __restrict__ TSH, float* __restrict__ TSP) {
    __shared__ alignas(16) short As[128 * 64];
    __shared__ alignas(16) short Bs[128 * 64];
    int z = blockIdx.z;
    const unsigned short* A = (z < 2) ? FIb : FTb;
    const unsigned short* W = z == 0 ? Wisp : z == 1 ? Wish : z == 2 ? Wtsh : Wtsp;
    const float* b = z == 0 ? bisp : z == 1 ? bish : z == 2 ? btsh : btsp;
    float* C = z == 0 ? ISP : z == 1 ? ISH : z == 2 ? TSH : TSP;
    gemm_body(A, W, b, nullptr, C, 128, 128, 0, 0, blockIdx.y, As, Bs);
}

// ---------------------------------------------------------------------------
// Row-normalize (z-batched, 4 tensors): out bf16. z<2 inputs bf16, else fp32.
// ---------------------------------------------------------------------------
__global__ void rownorm4(const unsigned short* __restrict__ fi, const unsigned short* __restrict__ ft,
                         const float* __restrict__ ish, const float* __restrict__ tsh,
                         unsigned short* __restrict__ fin, unsigned short* __restrict__ ftn,
                         unsigned short* __restrict__ ishn, unsigned short* __restrict__ tshn) {
    int z = blockIdx.y;
    int m = blockIdx.x * 256 + threadIdx.x;
    const unsigned short* sb = (z == 0) ? fi : ft;
    const float* sf = (z == 2) ? ish : tsh;
    unsigned short* dst = z == 0 ? fin : z == 1 ? ftn : z == 2 ? ishn : tshn;
    float ss = 0.f;
    if (z < 2) {
        for (int u = 0; u < 128; u += 8) {
            bf16x8 v = *(const bf16x8*)&sb[(size_t)m * 128 + u];
#pragma unroll
            for (int e = 0; e < 8; ++e) { float f = b2f((unsigned short)v[e]); ss += f * f; }
        }
    } else {
        for (int u = 0; u < 128; u += 4) {
            float4 v = *(const float4*)&sf[(size_t)m * 128 + u];
            ss += v.x * v.x + v.y * v.y + v.z * v.z + v.w * v.w;
        }
    }
    float inv = 1.f / fmaxf(sqrtf(ss), 1e-12f);
    if (z < 2) {
        for (int u = 0; u < 128; u += 8) {
            bf16x8 v = *(const bf16x8*)&sb[(size_t)m * 128 + u];
            ushort4 o0, o1;
            o0.x = f2b(b2f((unsigned short)v[0]) * inv); o0.y = f2b(b2f((unsigned short)v[1]) * inv);
            o0.z = f2b(b2f((unsigned short)v[2]) * inv); o0.w = f2b(b2f((unsigned short)v[3]) * inv);
            o1.x = f2b(b2f((unsigned short)v[4]) * inv); o1.y = f2b(b2f((unsigned short)v[5]) * inv);
            o1.z = f2b(b2f((unsigned short)v[6]) * inv); o1.w = f2b(b2f((unsigned short)v[7]) * inv);
            *(ushort4*)&dst[(size_t)m * 128 + u] = o0;
            *(ushort4*)&dst[(size_t)m * 128 + u + 4] = o1;
        }
    } else {
        for (int u = 0; u < 128; u += 4) {
            float4 v = *(const float4*)&sf[(size_t)m * 128 + u];
            ushort4 o;
            o.x = f2b(v.x * inv); o.y = f2b(v.y * inv); o.z = f2b(v.z * inv); o.w = f2b(v.w * inv);
            *(ushort4*)&dst[(size_t)m * 128 + u] = o;
        }
    }
}

// ---------------------------------------------------------------------------
// Count y==0 -> scal[0]
// ---------------------------------------------------------------------------
__global__ void county_kernel(const int* __restrict__ y, float* __restrict__ scal) {
    __shared__ int red[256];
    int t = threadIdx.x;
    int c = 0;
    for (int i = t; i < BSZ; i += 256) c += (y[i] == 0) ? 1 : 0;
    red[t] = c;
    __syncthreads();
    for (int s = 128; s > 0; s >>= 1) {
        if (t < s) red[t] += red[t + s];
        __syncthreads();
    }
    if (t == 0) scal[0] = (float)red[0];
}

// ---------------------------------------------------------------------------
// MFMA CLIP tile (z=2 merged): S = In @ Tn^T, 128x128 tile/block.
// NO GLOBAL ATOMICS: stats stored as per-block/wave partials into st
// (layout at top of file); finalize sums them.
// ---------------------------------------------------------------------------
__global__ __launch_bounds__(256) void clip_mfma(const unsigned short* __restrict__ In1,
                                                 const unsigned short* __restrict__ Tn1,
                                                 const unsigned short* __restrict__ In2,
                                                 const unsigned short* __restrict__ Tn2,
                                                 const int* __restrict__ y,
                                                 const float* __restrict__ scale_log1,
                                                 const float* __restrict__ scale_log2,
                                                 float* __restrict__ st1, float* __restrict__ st2) {
    __shared__ alignas(16) short As[128 * 128];
    __shared__ alignas(16) short Bs[128 * 128];
    const int z = blockIdx.z;
    const unsigned short* In = z ? In2 : In1;
    const unsigned short* Tn = z ? Tn2 : Tn1;
    const float* scale_log = z ? scale_log2 : scale_log1;
    float* st = z ? st2 : st1;
    const int tid = threadIdx.x;
    const int w = tid >> 6, lane = tid & 63, quad = lane >> 4, l15 = lane & 15;
    const int bx = blockIdx.x, by = blockIdx.y;
    const int r0 = by * 128, c0 = bx * 128;
    const int rw = (w >> 1) * 64, cw = (w & 1) * 64;
#pragma unroll
    for (int r = 0; r < 8; ++r) {
        int idx = r * 256 + tid;
        int row = idx >> 4, cbp = idx & 15;
        int col = ((cbp ^ (row & 7)) << 3);
        *(bf16x8*)&As[row * 128 + cbp * 8] = *(const bf16x8*)&In[(size_t)(r0 + row) * 128 + col];
        *(bf16x8*)&Bs[row * 128 + cbp * 8] = *(const bf16x8*)&Tn[(size_t)(c0 + row) * 128 + col];
    }
    __syncthreads();
    f32x4 acc[4][4];
#pragma unroll
    for (int i = 0; i < 4; ++i)
#pragma unroll
        for (int j = 0; j < 4; ++j) acc[i][j] = (f32x4){0.f, 0.f, 0.f, 0.f};
#pragma unroll
    for (int kb = 0; kb < 4; ++kb) {
        bf16x8 af[4], bfr[4];
        int cb = kb * 4 + quad;
#pragma unroll
        for (int i = 0; i < 4; ++i) {
            int row = rw + i * 16 + l15;
            af[i] = *(const bf16x8*)&As[row * 128 + ((cb ^ (row & 7)) << 3)];
        }
#pragma unroll
        for (int j = 0; j < 4; ++j) {
            int row = cw + j * 16 + l15;
            bfr[j] = *(const bf16x8*)&Bs[row * 128 + ((cb ^ (row & 7)) << 3)];
        }
#pragma unroll
        for (int i = 0; i < 4; ++i)
#pragma unroll
            for (int j = 0; j < 4; ++j)
                acc[i][j] = __builtin_amdgcn_mfma_f32_16x16x32_bf16(af[i], bfr[j], acc[i][j], 0, 0, 0);
    }

    const float s = expf(scale_log[0]);
    int yrow[4][4]; float mrow[4][4];
    int ycol[4];    float mcol[4];
#pragma unroll
    for (int i = 0; i < 4; ++i)
#pragma unroll
        for (int r = 0; r < 4; ++r) {
            int yy = y[r0 + rw + i * 16 + quad * 4 + r];
            yrow[i][r] = yy; mrow[i][r] = (yy == 0) ? 1.f : 0.f;
        }
#pragma unroll
    for (int j = 0; j < 4; ++j) {
        int yy = y[c0 + cw + j * 16 + l15];
        ycol[j] = yy; mcol[j] = (yy == 0) ? 1.f : 0.f;
    }
    float rZ[4][4] = {}, rF[4][4] = {}, rW[4][4] = {};
    float cZ[4] = {}, cE[4] = {}, cW[4] = {};
    float aAll = 0.f, aC0 = 0.f, aR0 = 0.f, aRC = 0.f;
#pragma unroll
    for (int i = 0; i < 4; ++i)
#pragma unroll
        for (int r = 0; r < 4; ++r) {
            float mr = mrow[i][r];
            int yr = yrow[i][r];
#pragma unroll
            for (int j = 0; j < 4; ++j) {
                float S = acc[i][j][r];
                float L = s * S;
                float e1 = __expf(L);
                float e2 = __expf(S);
                float msk = (yr == ycol[j]) ? 1.f : 0.f;
                rZ[i][r] += e1; rF[i][r] += e1 * L; rW[i][r] += e1 * msk;
                cZ[j] += e2;    cE[j] += e2 * S;    cW[j] += e2 * msk;
                float tmp = S * mcol[j];
                aAll += S; aC0 += tmp; aR0 += S * mr; aRC += tmp * mr;
            }
        }
    // row partials: part index = bx*2 + (cw>>6); plain stores, no atomics
    const int p_row = bx * 2 + (cw >> 6);
#pragma unroll
    for (int i = 0; i < 4; ++i)
#pragma unroll
        for (int r = 0; r < 4; ++r) {
#pragma unroll
            for (int m = 1; m < 16; m <<= 1) {
                rZ[i][r] += __shfl_xor(rZ[i][r], m);
                rF[i][r] += __shfl_xor(rF[i][r], m);
                rW[i][r] += __shfl_xor(rW[i][r], m);
            }
            if (l15 == (i * 4 + r)) {
                int grow = r0 + rw + i * 16 + quad * 4 + r;
                int base = ST_ROW + p_row * 4096 + grow;
                st[base]          = rZ[i][r];
                st[base + 262144] = rF[i][r];
                st[base + 524288] = rW[i][r];
            }
        }
    // col partials: part index = by*2 + (rw>>6)
    const int p_col = by * 2 + (rw >> 6);
#pragma unroll
    for (int j = 0; j < 4; ++j) {
        cZ[j] += __shfl_xor(cZ[j], 16); cZ[j] += __shfl_xor(cZ[j], 32);
        cE[j] += __shfl_xor(cE[j], 16); cE[j] += __shfl_xor(cE[j], 32);
        cW[j] += __shfl_xor(cW[j], 16); cW[j] += __shfl_xor(cW[j], 32);
        if (quad == 0) {
            int gcol = c0 + cw + j * 16 + l15;
            int base = ST_COL + p_col * 4096 + gcol;
            st[base]          = cZ[j];
            st[base + 262144] = cE[j];
            st[base + 524288] = cW[j];
        }
    }
    // T scalars: per-wave reduce, per-wave store (4096 waves x 4 floats)
#pragma unroll
    for (int m = 1; m < 64; m <<= 1) {
        aAll += __shfl_xor(aAll, m); aC0 += __shfl_xor(aC0, m);
        aR0 += __shfl_xor(aR0, m);   aRC += __shfl_xor(aRC, m);
    }
    if (lane == 0) {
        int wg = (by * 32 + bx) * 4 + w;
        float T00 = aRC, T01 = aR0 - aRC, T10 = aC0 - aRC, T11 = aAll - aR0 - aC0 + aRC;
        st[ST_T + wg * 4 + 0] = T00;
        st[ST_T + wg * 4 + 1] = T01;
        st[ST_T + wg * 4 + 2] = T10;
        st[ST_T + wg * 4 + 3] = T11;
    }
}

// ---------------------------------------------------------------------------
// CLIP finalize (z=2 merged): sum partials, per-k KL terms, T-scalar tail.
// ---------------------------------------------------------------------------
__global__ void clip_finalize(const float* __restrict__ st1, const float* __restrict__ st2,
                              const int* __restrict__ y,
                              const float* __restrict__ scale_log1, const float* __restrict__ scale_log2,
                              const float* __restrict__ scal, float* __restrict__ loss_base) {
    __shared__ float red[256];
    __shared__ float4 tred[256];
    const int z = blockIdx.y;
    const float* st = z ? st2 : st1;
    const float* scale_log = z ? scale_log2 : scale_log1;
    float* loss_slot = loss_base + z;
    int tid = threadIdx.x;
    int k = blockIdx.x * 256 + tid;
    const float Bf = (float)BSZ;
    const float n0 = scal[0];
    int yk = y[k];
    float n = (yk == 0) ? n0 : (Bf - n0);
    float a = 1.0f / n;
    float ea = expf(a);
    float denom = n * ea + (Bf - n);
    float q_s = ea / denom, q_d = 1.0f / denom;
    float ld = logf(denom);
    float lq_s = a - ld, lq_d = -ld;
    float Qlq = n * q_s * lq_s + (Bf - n) * q_d * lq_d;

    float Z1 = 0.f, F1 = 0.f, W1 = 0.f, Z2 = 0.f, E2 = 0.f, W2 = 0.f;
#pragma unroll 8
    for (int p = 0; p < 64; ++p) {
        int base = p * 4096 + k;
        Z1 += st[ST_ROW + base];
        F1 += st[ST_ROW + base + 262144];
        W1 += st[ST_ROW + base + 524288];
        Z2 += st[ST_COL + base];
        E2 += st[ST_COL + base + 262144];
        W2 += st[ST_COL + base + 524288];
    }
    float term_r = Qlq + F1 / Z1 - lq_d - (lq_s - lq_d) * (W1 / Z1);
    float term_c = Qlq + E2 / Z2 - lq_d - (lq_s - lq_d) * (W2 / Z2);
    float v = (term_r + term_c) / (4.0f * Bf);
    red[tid] = v;

    // block 0: cooperative T-partial reduction (4096 float4)
    if (blockIdx.x == 0) {
        const float4* tp = (const float4*)&st[ST_T];
        float4 acc = {0.f, 0.f, 0.f, 0.f};
        for (int u = tid; u < 4096; u += 256) {
            float4 t4 = tp[u];
            acc.x += t4.x; acc.y += t4.y; acc.z += t4.z; acc.w += t4.w;
        }
        tred[tid] = acc;
    }
    __syncthreads();
    for (int ss2 = 128; ss2 > 0; ss2 >>= 1) {
        if (tid < ss2) {
            red[tid] += red[tid + ss2];
            if (blockIdx.x == 0) {
                tred[tid].x += tred[tid + ss2].x; tred[tid].y += tred[tid + ss2].y;
                tred[tid].z += tred[tid + ss2].z; tred[tid].w += tred[tid + ss2].w;
            }
        }
        __syncthreads();
    }
    if (tid == 0) {
        float total = red[0];
        if (blockIdx.x == 0) {
            const float s = expf(scale_log[0]);
            float n1 = Bf - n0;
            float a0 = 1.f / n0, a1 = 1.f / n1;
            float e0 = expf(a0), e1 = expf(a1);
            float d0 = n0 * e0 + (Bf - n0), d1 = n1 * e1 + (Bf - n1);
            float qs0 = e0 / d0, qd0 = 1.f / d0, qs1 = e1 / d1, qd1 = 1.f / d1;
            float T00 = tred[0].x, T01 = tred[0].y, T10 = tred[0].z, T11 = tred[0].w;
            float QS1 = qd0 * (T00 + T01) + (qs0 - qd0) * T00 + qd1 * (T10 + T11) + (qs1 - qd1) * T11;
            float QS2 = qd0 * (T00 + T10) + (qs0 - qd0) * T00 + qd1 * (T01 + T11) + (qs1 - qd1) * T11;
            total += (-s * QS1 - QS2) / (4.0f * Bf);
        }
        atomicAdd(loss_slot, total);
    }
}

// ---------------------------------------------------------------------------
// Gram (z-batched over 4 matrices + 16 row-chunks)
// ---------------------------------------------------------------------------
__global__ void gram4(const float* __restrict__ isp, const float* __restrict__ ish,
                      const float* __restrict__ tsp, const float* __restrict__ tsh,
                      float* __restrict__ G) {
    int mat = blockIdx.z >> 4, chunk = blockIdx.z & 15;
    const float* A = mat == 0 ? isp : mat == 1 ? ish : mat == 2 ? tsp : tsh;
    float* Gm = G + mat * 16384;
    int a = blockIdx.y * 16 + threadIdx.y;
    int b = blockIdx.x * 16 + threadIdx.x;
    int m0 = chunk * 256;
    float acc = 0.0f;
    for (int m = m0; m < m0 + 256; ++m)
        acc += A[(size_t)m * 128 + a] * A[(size_t)m * 128 + b];
    atomicAdd(&Gm[a * 128 + b], acc);
}

__global__ void frob2(const float* __restrict__ G, float* __restrict__ scal) {
    __shared__ float red[256];
    int z = blockIdx.y;
    const float* GA = G + (z ? 2 : 0) * 16384;
    const float* GB = G + (z ? 3 : 1) * 16384;
    int t = threadIdx.x;
    float acc = 0.0f;
    for (int u = blockIdx.x * 256 + t; u < 16384; u += 16 * 256)
        acc += GA[u] * GB[u];
    red[t] = acc;
    __syncthreads();
    for (int s = 128; s > 0; s >>= 1) {
        if (t < s) red[t] += red[t + s];
        __syncthreads();
    }
    if (t == 0) atomicAdd(&scal[3 + z], red[0]);
}

// ---------------------------------------------------------------------------
// Scalar heads (z-batched): out[1 + z*BSZ + m] = dot(X[m], w) + b
// z: 0=(ISP,c1) 1=(ISH,c2) 2=(TSP,c4) 3=(TSH,c3)
// ---------------------------------------------------------------------------
__global__ void head4(const float* __restrict__ isp, const float* __restrict__ ish,
                      const float* __restrict__ tsp, const float* __restrict__ tsh,
                      const float* __restrict__ c1w, const float* __restrict__ c2w,
                      const float* __restrict__ c4w, const float* __restrict__ c3w,
                      const float* __restrict__ c1b, const float* __restrict__ c2b,
                      const float* __restrict__ c4b, const float* __restrict__ c3b,
                      float* __restrict__ out) {
    int z = blockIdx.y;
    const float* X = z == 0 ? isp : z == 1 ? ish : z == 2 ? tsp : tsh;
    const float* w = z == 0 ? c1w : z == 1 ? c2w : z == 2 ? c4w : c3w;
    const float* b = z == 0 ? c1b : z == 1 ? c2b : z == 2 ? c4b : c3b;
    int m = blockIdx.x * 256 + threadIdx.x;
    const float4* xp = (const float4*)(X + (size_t)m * 128);
    const float4* wp = (const float4*)w;
    float acc = 0.0f;
#pragma unroll
    for (int u = 0; u < 32; ++u) {
        float4 av = xp[u], cv = wp[u];
        acc += av.x * cv.x + av.y * cv.y + av.z * cv.z + av.w * cv.w;
    }
    out[1 + (size_t)z * BSZ + m] = acc + b[0];
}

__global__ void final_kernel(const float* __restrict__ scal, float* __restrict__ out) {
    float loss1 = scal[1];
    float loss_sh = scal[2];
    float ss_i = scal[3];
    float ss_t = scal[4];
    float loss_sp = 0.5f * (sqrtf(ss_t) + sqrtf(ss_i));
    out[0] = (loss_sp + loss_sh + loss1) / 3.0f;
}

// ---------------------------------------------------------------------------
extern "C" void kernel_launch(void* const* d_in, const int* in_sizes, int n_in,
                              void* d_out, int out_size, void* d_ws, size_t ws_size,
                              hipStream_t stream) {
    const float* i_in  = (const float*)d_in[0];
    const float* t_in  = (const float*)d_in[1];
    const int*   y     = (const int*)d_in[2];
    const float* l1_w  = (const float*)d_in[3];
    const float* l1_b  = (const float*)d_in[4];
    const float* l2_w  = (const float*)d_in[5];
    const float* l2_b  = (const float*)d_in[6];
    const float* l3_w  = (const float*)d_in[7];
    const float* l3_b  = (const float*)d_in[8];
    const float* tl1_w = (const float*)d_in[9];
    const float* tl1_b = (const float*)d_in[10];
    const float* tl2_w = (const float*)d_in[11];
    const float* tl2_b = (const float*)d_in[12];
    const float* isp_w = (const float*)d_in[13];
    const float* isp_b = (const float*)d_in[14];
    const float* ish_w = (const float*)d_in[15];
    const float* ish_b = (const float*)d_in[16];
    const float* tsh_w = (const float*)d_in[17];
    const float* tsh_b = (const float*)d_in[18];
    const float* tsp_w = (const float*)d_in[19];
    const float* tsp_b = (const float*)d_in[20];
    const float* c1_w  = (const float*)d_in[21];
    const float* c1_b  = (const float*)d_in[22];
    const float* c2_w  = (const float*)d_in[23];
    const float* c2_b  = (const float*)d_in[24];
    const float* c3_w  = (const float*)d_in[25];
    const float* c3_b  = (const float*)d_in[26];
    const float* c4_w  = (const float*)d_in[27];
    const float* c4_b  = (const float*)d_in[28];
    const float* scale1 = (const float*)d_in[29];
    const float* scale2 = (const float*)d_in[30];

    float* ws = (float*)d_ws;
    // zeroed fp32 region (small): SCAL + GMS only
    float* SCAL = ws;                       // 64
    float* GMS  = ws + 64;                  // 4*16384 = 65536
    // fp32 work buffers
    float* ISP  = GMS + 65536;
    float* ISH  = ISP + (size_t)BSZ * 128;
    float* TSP  = ISH + (size_t)BSZ * 128;
    float* TSH  = TSP + (size_t)BSZ * 128;
    // bf16 buffers
    unsigned short* IB   = (unsigned short*)(TSH + (size_t)BSZ * 128);
    unsigned short* WB   = IB + (size_t)BSZ * 2048;      // 1294336
    unsigned short* FI1B = WB + 1294336;                 // 4096*512
    unsigned short* FI2B = FI1B + (size_t)BSZ * 512;     // 4096*256
    unsigned short* FIB  = FI2B + (size_t)BSZ * 256;     // 4096*128
    unsigned short* FT1B = FIB + (size_t)BSZ * 128;
    unsigned short* FTB  = FT1B + (size_t)BSZ * 128;
    unsigned short* FINB = FTB + (size_t)BSZ * 128;
    unsigned short* FTNB = FINB + (size_t)BSZ * 128;
    unsigned short* ISHN = FTNB + (size_t)BSZ * 128;
    unsigned short* TSHN = ISHN + (size_t)BSZ * 128;
    // ST partial buffers ALIAS IB (16.8 MB): IB is fully consumed by the L1
    // mfma_gemm, which completes (stream order) before clip_mfma writes ST.
    float* ST1 = (float*)IB;                 // 1589248 floats
    float* ST2 = ST1 + ST_FLOATS;            // 1589248 floats (12.1 MB total)

    float* out = (float*)d_out;

    hipMemsetAsync(d_ws, 0, (64 + 65536) * sizeof(float), stream);
    county_kernel<<<1, 256, 0, stream>>>(y, SCAL);
    cast_kernel<<<8192, 256, 0, stream>>>(i_in, IB, BSZ * 2048);
    cast_w_kernel<<<1264, 256, 0, stream>>>(l1_w, l2_w, l3_w, tl2_w, isp_w, ish_w, tsh_w, tsp_w, WB);
    gemm_small<<<dim3(2, 64), dim3(16, 16), 0, stream>>>(t_in, tl1_w, tl1_b, FT1B, BSZ, 128, 49, 1);

    mfma_gemm<<<dim3(4, 32), 256, 0, stream>>>(IB, WB, l1_b, FI1B, nullptr, 512, 2048, 1);
    mfma_gemm<<<dim3(2, 32), 256, 0, stream>>>(FI1B, WB + 1048576, l2_b, FI2B, nullptr, 256, 512, 1);
    mfma_gemm<<<dim3(1, 32), 256, 0, stream>>>(FI2B, WB + 1179648, l3_b, FIB, nullptr, 128, 256, 0);
    mfma_gemm<<<dim3(1, 32), 256, 0, stream>>>(FT1B, WB + 1212416, tl2_b, FTB, nullptr, 128, 128, 0);
    mfma_heads<<<dim3(1, 32, 4), 256, 0, stream>>>(FIB, FTB, WB + 1228800, WB + 1245184, WB + 1261568,
                                                   WB + 1277952, isp_b, ish_b, tsh_b, tsp_b,
                                                   ISP, ISH, TSH, TSP);
    rownorm4<<<dim3(16, 4), 256, 0, stream>>>(FIB, FTB, ISH, TSH, FINB, FTNB, ISHN, TSHN);

    clip_mfma<<<dim3(32, 32, 2), 256, 0, stream>>>(FINB, FTNB, ISHN, TSHN, y, scale1, scale2, ST1, ST2);
    clip_finalize<<<dim3(16, 2), 256, 0, stream>>>(ST1, ST2, y, scale1, scale2, SCAL, &SCAL[1]);

    gram4<<<dim3(8, 8, 64), dim3(16, 16), 0, stream>>>(ISP, ISH, TSP, TSH, GMS);
    frob2<<<dim3(16, 2), 256, 0, stream>>>(GMS, SCAL);
    head4<<<dim3(16, 4), 256, 0, stream>>>(ISP, ISH, TSP, TSH, c1_w, c2_w, c4_w, c3_w,
                                           c1_b, c2_b, c4_b, c3_b, out);
    final_kernel<<<1, 1, 0, stream>>>(SCAL, out);
}

// Round 5
// 350.642 us; speedup vs baseline: 3.6019x; 1.1060x over previous
//
#include <hip/hip_runtime.h>
#include <math.h>

#define BSZ 4096

typedef __attribute__((ext_vector_type(8))) short bf16x8;
typedef __attribute__((ext_vector_type(4))) float f32x4;

// ST layout (floats): rowZ@0, rowF@262144, rowW@524288 (each [64 part][4096 row])
//                     colZ@786432, colE@1048576, colW@1310720
//                     Tpart@1572864 ([4096 waves][4])
#define ST_ROW 0
#define ST_COL 786432
#define ST_T   1572864
#define ST_FLOATS 1589248

__device__ __forceinline__ unsigned short f2b(float f) {
    unsigned u = __float_as_uint(f);
    u = u + 0x7fffu + ((u >> 16) & 1u);
    return (unsigned short)(u >> 16);
}
__device__ __forceinline__ float b2f(unsigned short s) {
    return __uint_as_float(((unsigned)s) << 16);
}

// ---------------------------------------------------------------------------
// fp32 -> bf16 cast, 4 elems/thread (n multiple of 4)
// ---------------------------------------------------------------------------
__global__ void cast_kernel(const float* __restrict__ x, unsigned short* __restrict__ o, int n) {
    int i = (blockIdx.x * 256 + threadIdx.x) * 4;
    if (i >= n) return;
    float4 v = *(const float4*)(x + i);
    ushort4 r;
    r.x = f2b(v.x); r.y = f2b(v.y); r.z = f2b(v.z); r.w = f2b(v.w);
    *(ushort4*)(o + i) = r;
}

// Combined weight cast into one packed bf16 buffer (compile-time offsets).
__global__ void cast_w_kernel(const float* __restrict__ l1, const float* __restrict__ l2,
                              const float* __restrict__ l3, const float* __restrict__ tl2,
                              const float* __restrict__ isp, const float* __restrict__ ish,
                              const float* __restrict__ tsh, const float* __restrict__ tsp,
                              unsigned short* __restrict__ o) {
    int i = (blockIdx.x * 256 + threadIdx.x) * 4;
    if (i >= 1294336) return;
    const float* src; int off;
    if (i < 1048576)      { src = l1;  off = 0; }
    else if (i < 1179648) { src = l2;  off = 1048576; }
    else if (i < 1212416) { src = l3;  off = 1179648; }
    else if (i < 1228800) { src = tl2; off = 1212416; }
    else if (i < 1245184) { src = isp; off = 1228800; }
    else if (i < 1261568) { src = ish; off = 1245184; }
    else if (i < 1277952) { src = tsh; off = 1261568; }
    else                  { src = tsp; off = 1277952; }
    float4 v = *(const float4*)(src + (i - off));
    ushort4 r;
    r.x = f2b(v.x); r.y = f2b(v.y); r.z = f2b(v.z); r.w = f2b(v.w);
    *(ushort4*)(o + i) = r;
}

// ---------------------------------------------------------------------------
// SIMT GEMM (only for tl1, K=49), bf16 output. A:[M,K] f32, W:[N,K] f32.
// ---------------------------------------------------------------------------
__global__ void gemm_small(const float* __restrict__ A, const float* __restrict__ W,
                           const float* __restrict__ bias, unsigned short* __restrict__ C,
                           int M, int N, int K, int relu) {
    __shared__ float As[16][65];
    __shared__ float Ws[16][65];
    const int tx = threadIdx.x, ty = threadIdx.y;
    const int tid = ty * 16 + tx;
    const int m0 = blockIdx.y * 64, n0 = blockIdx.x * 64;
    float acc[4][4] = {};
    const int lrow = tid >> 2;
    const int lkb = (tid & 3) * 4;
    for (int k0 = 0; k0 < K; k0 += 16) {
#pragma unroll
        for (int u = 0; u < 4; ++u) {
            int k = k0 + lkb + u;
            As[lkb + u][lrow] = (k < K) ? A[(size_t)(m0 + lrow) * K + k] : 0.0f;
            Ws[lkb + u][lrow] = (k < K) ? W[(size_t)(n0 + lrow) * K + k] : 0.0f;
        }
        __syncthreads();
#pragma unroll
        for (int kk = 0; kk < 16; ++kk) {
            float av[4], bv[4];
#pragma unroll
            for (int i = 0; i < 4; ++i) av[i] = As[kk][ty * 4 + i];
#pragma unroll
            for (int j = 0; j < 4; ++j) bv[j] = Ws[kk][tx * 4 + j];
#pragma unroll
            for (int i = 0; i < 4; ++i)
#pragma unroll
                for (int j = 0; j < 4; ++j) acc[i][j] += av[i] * bv[j];
        }
        __syncthreads();
    }
#pragma unroll
    for (int i = 0; i < 4; ++i)
#pragma unroll
        for (int j = 0; j < 4; ++j) {
            int n = n0 + tx * 4 + j;
            float v = acc[i][j] + bias[n];
            if (relu) v = fmaxf(v, 0.0f);
            C[(size_t)(m0 + ty * 4 + i) * N + n] = f2b(v);
        }
}

// ---------------------------------------------------------------------------
// MFMA GEMM body: C = act(A @ W^T + bias). A:[M,K] bf16, W:[N,K] bf16.
// Tile 128x128, 4 waves (2x2 of 64x64), BK=64, 16x16x32 bf16 MFMA.
// LDS XOR-swizzle: LDS[row][cbp] holds global col-block (cbp ^ (row&7)).
// ---------------------------------------------------------------------------
__device__ __forceinline__ void gemm_body(const unsigned short* __restrict__ A,
                                          const unsigned short* __restrict__ W,
                                          const float* __restrict__ bias,
                                          unsigned short* __restrict__ Cb,
                                          float* __restrict__ Cf,
                                          int N, int K, int relu, int bx, int by,
                                          short* As, short* Bs) {
    const int tid = threadIdx.x;
    const int w = tid >> 6, lane = tid & 63, quad = lane >> 4, l15 = lane & 15;
    const int m0 = by * 128, n0 = bx * 128;
    const int rw = (w >> 1) * 64, cw = (w & 1) * 64;
    f32x4 acc[4][4];
#pragma unroll
    for (int i = 0; i < 4; ++i)
#pragma unroll
        for (int j = 0; j < 4; ++j) acc[i][j] = (f32x4){0.f, 0.f, 0.f, 0.f};

    for (int k0 = 0; k0 < K; k0 += 64) {
#pragma unroll
        for (int r = 0; r < 4; ++r) {
            int idx = r * 256 + tid;
            int row = idx >> 3, cbp = idx & 7;
            int col = ((cbp ^ (row & 7)) << 3);
            *(bf16x8*)&As[row * 64 + cbp * 8] = *(const bf16x8*)&A[(size_t)(m0 + row) * K + k0 + col];
            *(bf16x8*)&Bs[row * 64 + cbp * 8] = *(const bf16x8*)&W[(size_t)(n0 + row) * K + k0 + col];
        }
        __syncthreads();
#pragma unroll
        for (int kb = 0; kb < 2; ++kb) {
            bf16x8 af[4], bfr[4];
            int cb = kb * 4 + quad;
#pragma unroll
            for (int i = 0; i < 4; ++i) {
                int row = rw + i * 16 + l15;
                af[i] = *(const bf16x8*)&As[row * 64 + ((cb ^ (row & 7)) << 3)];
            }
#pragma unroll
            for (int j = 0; j < 4; ++j) {
                int row = cw + j * 16 + l15;
                bfr[j] = *(const bf16x8*)&Bs[row * 64 + ((cb ^ (row & 7)) << 3)];
            }
#pragma unroll
            for (int i = 0; i < 4; ++i)
#pragma unroll
                for (int j = 0; j < 4; ++j)
                    acc[i][j] = __builtin_amdgcn_mfma_f32_16x16x32_bf16(af[i], bfr[j], acc[i][j], 0, 0, 0);
        }
        __syncthreads();
    }
    // epilogue: C/D layout col=lane&15 (n), row=quad*4+reg (m)
#pragma unroll
    for (int j = 0; j < 4; ++j) {
        int n = n0 + cw + j * 16 + l15;
        float bv = bias[n];
#pragma unroll
        for (int i = 0; i < 4; ++i) {
#pragma unroll
            for (int r = 0; r < 4; ++r) {
                int m = m0 + rw + i * 16 + quad * 4 + r;
                float v = acc[i][j][r] + bv;
                if (relu) v = fmaxf(v, 0.f);
                if (Cb) Cb[(size_t)m * N + n] = f2b(v);
                if (Cf) Cf[(size_t)m * N + n] = v;
            }
        }
    }
}

__global__ __launch_bounds__(256) void mfma_gemm(const unsigned short* __restrict__ A,
                                                 const unsigned short* __restrict__ W,
                                                 const float* __restrict__ bias,
                                                 unsigned short* __restrict__ Cb,
                                                 float* __restrict__ Cf, int N, int K, int relu) {
    __shared__ alignas(16) short As[128 * 64];
    __shared__ alignas(16) short Bs[128 * 64];
    gemm_body(A, W, bias, Cb, Cf, N, K, relu, blockIdx.x, blockIdx.y, As, Bs);
}

// Batched SS heads: z selects (input, weight, bias, out). N=K=128, fp32 out.
__global__ __launch_bounds__(256) void mfma_heads(const unsigned short* __restrict__ FIb,
                                                  const unsigned short* __restrict__ FTb,
                                                  const unsigned short* __restrict__ Wisp,
                                                  const unsigned short* __restrict__ Wish,
                                                  const unsigned short* __restrict__ Wtsh,
                                                  const unsigned short* __restrict__ Wtsp,
                                                  const float* __restrict__ bisp, const float* __restrict__ bish,
                                                  const float* __restrict__ btsh, const float* __restrict__ btsp,
                                                  float* __restrict__ ISP, float* __restrict__ ISH,
                                                  float* __restrict__ TSH, float* __restrict__ TSP) {
    __shared__ alignas(16) short As[128 * 64];
    __shared__ alignas(16) short Bs[128 * 64];
    int z = blockIdx.z;
    const unsigned short* A = (z < 2) ? FIb : FTb;
    const unsigned short* W = z == 0 ? Wisp : z == 1 ? Wish : z == 2 ? Wtsh : Wtsp;
    const float* b = z == 0 ? bisp : z == 1 ? bish : z == 2 ? btsh : btsp;
    float* C = z == 0 ? ISP : z == 1 ? ISH : z == 2 ? TSH : TSP;
    gemm_body(A, W, b, nullptr, C, 128, 128, 0, 0, blockIdx.y, As, Bs);
}

// ---------------------------------------------------------------------------
// Row-normalize (z-batched, 4 tensors): out bf16. z<2 inputs bf16, else fp32.
// ---------------------------------------------------------------------------
__global__ void rownorm4(const unsigned short* __restrict__ fi, const unsigned short* __restrict__ ft,
                         const float* __restrict__ ish, const float* __restrict__ tsh,
                         unsigned short* __restrict__ fin, unsigned short* __restrict__ ftn,
                         unsigned short* __restrict__ ishn, unsigned short* __restrict__ tshn) {
    int z = blockIdx.y;
    int m = blockIdx.x * 256 + threadIdx.x;
    const unsigned short* sb = (z == 0) ? fi : ft;
    const float* sf = (z == 2) ? ish : tsh;
    unsigned short* dst = z == 0 ? fin : z == 1 ? ftn : z == 2 ? ishn : tshn;
    float ss = 0.f;
    if (z < 2) {
        for (int u = 0; u < 128; u += 8) {
            bf16x8 v = *(const bf16x8*)&sb[(size_t)m * 128 + u];
#pragma unroll
            for (int e = 0; e < 8; ++e) { float f = b2f((unsigned short)v[e]); ss += f * f; }
        }
    } else {
        for (int u = 0; u < 128; u += 4) {
            float4 v = *(const float4*)&sf[(size_t)m * 128 + u];
            ss += v.x * v.x + v.y * v.y + v.z * v.z + v.w * v.w;
        }
    }
    float inv = 1.f / fmaxf(sqrtf(ss), 1e-12f);
    if (z < 2) {
        for (int u = 0; u < 128; u += 8) {
            bf16x8 v = *(const bf16x8*)&sb[(size_t)m * 128 + u];
            ushort4 o0, o1;
            o0.x = f2b(b2f((unsigned short)v[0]) * inv); o0.y = f2b(b2f((unsigned short)v[1]) * inv);
            o0.z = f2b(b2f((unsigned short)v[2]) * inv); o0.w = f2b(b2f((unsigned short)v[3]) * inv);
            o1.x = f2b(b2f((unsigned short)v[4]) * inv); o1.y = f2b(b2f((unsigned short)v[5]) * inv);
            o1.z = f2b(b2f((unsigned short)v[6]) * inv); o1.w = f2b(b2f((unsigned short)v[7]) * inv);
            *(ushort4*)&dst[(size_t)m * 128 + u] = o0;
            *(ushort4*)&dst[(size_t)m * 128 + u + 4] = o1;
        }
    } else {
        for (int u = 0; u < 128; u += 4) {
            float4 v = *(const float4*)&sf[(size_t)m * 128 + u];
            ushort4 o;
            o.x = f2b(v.x * inv); o.y = f2b(v.y * inv); o.z = f2b(v.z * inv); o.w = f2b(v.w * inv);
            *(ushort4*)&dst[(size_t)m * 128 + u] = o;
        }
    }
}

// ---------------------------------------------------------------------------
// MFMA CLIP tile (z=2 merged): S = In @ Tn^T, 128x128 tile/block.
// NO GLOBAL ATOMICS: stats stored as per-block/wave partials into st
// (layout at top of file); finalize sums them.
// ---------------------------------------------------------------------------
__global__ __launch_bounds__(256) void clip_mfma(const unsigned short* __restrict__ In1,
                                                 const unsigned short* __restrict__ Tn1,
                                                 const unsigned short* __restrict__ In2,
                                                 const unsigned short* __restrict__ Tn2,
                                                 const int* __restrict__ y,
                                                 const float* __restrict__ scale_log1,
                                                 const float* __restrict__ scale_log2,
                                                 float* __restrict__ st1, float* __restrict__ st2) {
    __shared__ alignas(16) short As[128 * 128];
    __shared__ alignas(16) short Bs[128 * 128];
    const int z = blockIdx.z;
    const unsigned short* In = z ? In2 : In1;
    const unsigned short* Tn = z ? Tn2 : Tn1;
    const float* scale_log = z ? scale_log2 : scale_log1;
    float* st = z ? st2 : st1;
    const int tid = threadIdx.x;
    const int w = tid >> 6, lane = tid & 63, quad = lane >> 4, l15 = lane & 15;
    const int bx = blockIdx.x, by = blockIdx.y;
    const int r0 = by * 128, c0 = bx * 128;
    const int rw = (w >> 1) * 64, cw = (w & 1) * 64;
#pragma unroll
    for (int r = 0; r < 8; ++r) {
        int idx = r * 256 + tid;
        int row = idx >> 4, cbp = idx & 15;
        int col = ((cbp ^ (row & 7)) << 3);
        *(bf16x8*)&As[row * 128 + cbp * 8] = *(const bf16x8*)&In[(size_t)(r0 + row) * 128 + col];
        *(bf16x8*)&Bs[row * 128 + cbp * 8] = *(const bf16x8*)&Tn[(size_t)(c0 + row) * 128 + col];
    }
    __syncthreads();
    f32x4 acc[4][4];
#pragma unroll
    for (int i = 0; i < 4; ++i)
#pragma unroll
        for (int j = 0; j < 4; ++j) acc[i][j] = (f32x4){0.f, 0.f, 0.f, 0.f};
#pragma unroll
    for (int kb = 0; kb < 4; ++kb) {
        bf16x8 af[4], bfr[4];
        int cb = kb * 4 + quad;
#pragma unroll
        for (int i = 0; i < 4; ++i) {
            int row = rw + i * 16 + l15;
            af[i] = *(const bf16x8*)&As[row * 128 + ((cb ^ (row & 7)) << 3)];
        }
#pragma unroll
        for (int j = 0; j < 4; ++j) {
            int row = cw + j * 16 + l15;
            bfr[j] = *(const bf16x8*)&Bs[row * 128 + ((cb ^ (row & 7)) << 3)];
        }
#pragma unroll
        for (int i = 0; i < 4; ++i)
#pragma unroll
            for (int j = 0; j < 4; ++j)
                acc[i][j] = __builtin_amdgcn_mfma_f32_16x16x32_bf16(af[i], bfr[j], acc[i][j], 0, 0, 0);
    }

    const float s = expf(scale_log[0]);
    int yrow[4][4]; float mrow[4][4];
    int ycol[4];    float mcol[4];
#pragma unroll
    for (int i = 0; i < 4; ++i)
#pragma unroll
        for (int r = 0; r < 4; ++r) {
            int yy = y[r0 + rw + i * 16 + quad * 4 + r];
            yrow[i][r] = yy; mrow[i][r] = (yy == 0) ? 1.f : 0.f;
        }
#pragma unroll
    for (int j = 0; j < 4; ++j) {
        int yy = y[c0 + cw + j * 16 + l15];
        ycol[j] = yy; mcol[j] = (yy == 0) ? 1.f : 0.f;
    }
    float rZ[4][4] = {}, rF[4][4] = {}, rW[4][4] = {};
    float cZ[4] = {}, cE[4] = {}, cW[4] = {};
    float aAll = 0.f, aC0 = 0.f, aR0 = 0.f, aRC = 0.f;
#pragma unroll
    for (int i = 0; i < 4; ++i)
#pragma unroll
        for (int r = 0; r < 4; ++r) {
            float mr = mrow[i][r];
            int yr = yrow[i][r];
#pragma unroll
            for (int j = 0; j < 4; ++j) {
                float S = acc[i][j][r];
                float L = s * S;
                float e1 = __expf(L);
                float e2 = __expf(S);
                float msk = (yr == ycol[j]) ? 1.f : 0.f;
                rZ[i][r] += e1; rF[i][r] += e1 * L; rW[i][r] += e1 * msk;
                cZ[j] += e2;    cE[j] += e2 * S;    cW[j] += e2 * msk;
                float tmp = S * mcol[j];
                aAll += S; aC0 += tmp; aR0 += S * mr; aRC += tmp * mr;
            }
        }
    // row partials: part index = bx*2 + (cw>>6); plain stores, no atomics
    const int p_row = bx * 2 + (cw >> 6);
#pragma unroll
    for (int i = 0; i < 4; ++i)
#pragma unroll
        for (int r = 0; r < 4; ++r) {
#pragma unroll
            for (int m = 1; m < 16; m <<= 1) {
                rZ[i][r] += __shfl_xor(rZ[i][r], m);
                rF[i][r] += __shfl_xor(rF[i][r], m);
                rW[i][r] += __shfl_xor(rW[i][r], m);
            }
            if (l15 == (i * 4 + r)) {
                int grow = r0 + rw + i * 16 + quad * 4 + r;
                int base = ST_ROW + p_row * 4096 + grow;
                st[base]          = rZ[i][r];
                st[base + 262144] = rF[i][r];
                st[base + 524288] = rW[i][r];
            }
        }
    // col partials: part index = by*2 + (rw>>6)
    const int p_col = by * 2 + (rw >> 6);
#pragma unroll
    for (int j = 0; j < 4; ++j) {
        cZ[j] += __shfl_xor(cZ[j], 16); cZ[j] += __shfl_xor(cZ[j], 32);
        cE[j] += __shfl_xor(cE[j], 16); cE[j] += __shfl_xor(cE[j], 32);
        cW[j] += __shfl_xor(cW[j], 16); cW[j] += __shfl_xor(cW[j], 32);
        if (quad == 0) {
            int gcol = c0 + cw + j * 16 + l15;
            int base = ST_COL + p_col * 4096 + gcol;
            st[base]          = cZ[j];
            st[base + 262144] = cE[j];
            st[base + 524288] = cW[j];
        }
    }
    // T scalars: per-wave reduce, per-wave store (4096 waves x 4 floats)
#pragma unroll
    for (int m = 1; m < 64; m <<= 1) {
        aAll += __shfl_xor(aAll, m); aC0 += __shfl_xor(aC0, m);
        aR0 += __shfl_xor(aR0, m);   aRC += __shfl_xor(aRC, m);
    }
    if (lane == 0) {
        int wg = (by * 32 + bx) * 4 + w;
        float T00 = aRC, T01 = aR0 - aRC, T10 = aC0 - aRC, T11 = aAll - aR0 - aC0 + aRC;
        st[ST_T + wg * 4 + 0] = T00;
        st[ST_T + wg * 4 + 1] = T01;
        st[ST_T + wg * 4 + 2] = T10;
        st[ST_T + wg * 4 + 3] = T11;
    }
}

// ---------------------------------------------------------------------------
// CLIP finalize (z=2 merged): sum partials, per-k KL terms, T-scalar tail.
// n0 (count of y==0) computed per-block (county kernel folded in).
// ---------------------------------------------------------------------------
__global__ void clip_finalize(const float* __restrict__ st1, const float* __restrict__ st2,
                              const int* __restrict__ y,
                              const float* __restrict__ scale_log1, const float* __restrict__ scale_log2,
                              float* __restrict__ loss_base) {
    __shared__ float red[256];
    __shared__ float4 tred[256];
    const int z = blockIdx.y;
    const float* st = z ? st2 : st1;
    const float* scale_log = z ? scale_log2 : scale_log1;
    float* loss_slot = loss_base + z;
    int tid = threadIdx.x;
    int k = blockIdx.x * 256 + tid;
    const float Bf = (float)BSZ;

    // fold-in of county: block-local count of y==0
    float ccnt = 0.f;
    for (int i = tid; i < BSZ; i += 256) ccnt += (y[i] == 0) ? 1.f : 0.f;
    red[tid] = ccnt;
    __syncthreads();
    for (int ss2 = 128; ss2 > 0; ss2 >>= 1) {
        if (tid < ss2) red[tid] += red[tid + ss2];
        __syncthreads();
    }
    const float n0 = red[0];
    __syncthreads();

    int yk = y[k];
    float n = (yk == 0) ? n0 : (Bf - n0);
    float a = 1.0f / n;
    float ea = expf(a);
    float denom = n * ea + (Bf - n);
    float q_s = ea / denom, q_d = 1.0f / denom;
    float ld = logf(denom);
    float lq_s = a - ld, lq_d = -ld;
    float Qlq = n * q_s * lq_s + (Bf - n) * q_d * lq_d;

    float Z1 = 0.f, F1 = 0.f, W1 = 0.f, Z2 = 0.f, E2 = 0.f, W2 = 0.f;
#pragma unroll 8
    for (int p = 0; p < 64; ++p) {
        int base = p * 4096 + k;
        Z1 += st[ST_ROW + base];
        F1 += st[ST_ROW + base + 262144];
        W1 += st[ST_ROW + base + 524288];
        Z2 += st[ST_COL + base];
        E2 += st[ST_COL + base + 262144];
        W2 += st[ST_COL + base + 524288];
    }
    float term_r = Qlq + F1 / Z1 - lq_d - (lq_s - lq_d) * (W1 / Z1);
    float term_c = Qlq + E2 / Z2 - lq_d - (lq_s - lq_d) * (W2 / Z2);
    float v = (term_r + term_c) / (4.0f * Bf);
    red[tid] = v;

    // block 0: cooperative T-partial reduction (4096 float4)
    if (blockIdx.x == 0) {
        const float4* tp = (const float4*)&st[ST_T];
        float4 acc = {0.f, 0.f, 0.f, 0.f};
        for (int u = tid; u < 4096; u += 256) {
            float4 t4 = tp[u];
            acc.x += t4.x; acc.y += t4.y; acc.z += t4.z; acc.w += t4.w;
        }
        tred[tid] = acc;
    }
    __syncthreads();
    for (int ss2 = 128; ss2 > 0; ss2 >>= 1) {
        if (tid < ss2) {
            red[tid] += red[tid + ss2];
            if (blockIdx.x == 0) {
                tred[tid].x += tred[tid + ss2].x; tred[tid].y += tred[tid + ss2].y;
                tred[tid].z += tred[tid + ss2].z; tred[tid].w += tred[tid + ss2].w;
            }
        }
        __syncthreads();
    }
    if (tid == 0) {
        float total = red[0];
        if (blockIdx.x == 0) {
            const float s = expf(scale_log[0]);
            float n1 = Bf - n0;
            float a0 = 1.f / n0, a1 = 1.f / n1;
            float e0 = expf(a0), e1 = expf(a1);
            float d0 = n0 * e0 + (Bf - n0), d1 = n1 * e1 + (Bf - n1);
            float qs0 = e0 / d0, qd0 = 1.f / d0, qs1 = e1 / d1, qd1 = 1.f / d1;
            float T00 = tred[0].x, T01 = tred[0].y, T10 = tred[0].z, T11 = tred[0].w;
            float QS1 = qd0 * (T00 + T01) + (qs0 - qd0) * T00 + qd1 * (T10 + T11) + (qs1 - qd1) * T11;
            float QS2 = qd0 * (T00 + T10) + (qs0 - qd0) * T00 + qd1 * (T01 + T11) + (qs1 - qd1) * T11;
            total += (-s * QS1 - QS2) / (4.0f * Bf);
        }
        atomicAdd(loss_slot, total);
    }
}

// ---------------------------------------------------------------------------
// gram_splitk: G_mat = X^T X (128x128, K=4096) split-K in 64-row chunks, fp32.
// CORRECT separate-loss math (R3 formulation): ||A@B^T||_F^2 = sum (A^T A)∘(B^T B).
// grid (64, 4): y = mat (0=ISP,1=ISH,2=TSP,3=TSH). Partials to GP (no atomics).
// ---------------------------------------------------------------------------
__global__ __launch_bounds__(256) void gram_splitk(const float* __restrict__ isp,
                                                   const float* __restrict__ ish,
                                                   const float* __restrict__ tsp,
                                                   const float* __restrict__ tsh,
                                                   float* __restrict__ GP) {
    __shared__ alignas(16) float As2[64][128];
    const int mat = blockIdx.y, chunk = blockIdx.x;
    const float* A = mat == 0 ? isp : mat == 1 ? ish : mat == 2 ? tsp : tsh;
    const int tid = threadIdx.x;
    const int m0 = chunk * 64;
#pragma unroll
    for (int r = 0; r < 8; ++r) {
        int idx = r * 256 + tid;
        int row = idx >> 5, c4 = (idx & 31) * 4;
        *(float4*)&As2[row][c4] = *(const float4*)&A[(size_t)(m0 + row) * 128 + c4];
    }
    __syncthreads();
    const int ty = tid >> 4, tx = tid & 15;
    float acc[8][8] = {};
    for (int k = 0; k < 64; ++k) {
        float av[8], bv[8];
        *(float4*)&av[0] = *(const float4*)&As2[k][ty * 8];
        *(float4*)&av[4] = *(const float4*)&As2[k][ty * 8 + 4];
        *(float4*)&bv[0] = *(const float4*)&As2[k][tx * 8];
        *(float4*)&bv[4] = *(const float4*)&As2[k][tx * 8 + 4];
#pragma unroll
        for (int i = 0; i < 8; ++i)
#pragma unroll
            for (int j = 0; j < 8; ++j) acc[i][j] += av[i] * bv[j];
    }
    float* Gp = GP + ((size_t)(mat * 64 + chunk) << 14);
#pragma unroll
    for (int i = 0; i < 8; ++i) {
        *(float4*)&Gp[(ty * 8 + i) * 128 + tx * 8]     = *(float4*)&acc[i][0];
        *(float4*)&Gp[(ty * 8 + i) * 128 + tx * 8 + 4] = *(float4*)&acc[i][4];
    }
}

// frob_combine: per entry sum 64 K-partials of each Gram in the pair,
// multiply, reduce -> scal[3+z]. z=0: (ISP,ISH), z=1: (TSP,TSH).
__global__ void frob_combine(const float* __restrict__ GP, float* __restrict__ scal) {
    __shared__ float red[256];
    const int z = blockIdx.y;
    const int tid = threadIdx.x;
    int u = blockIdx.x * 1024 + tid * 4;
    float4 ga = {0.f, 0.f, 0.f, 0.f};
    float4 gb = {0.f, 0.f, 0.f, 0.f};
    const size_t baseA = ((size_t)(2 * z) * 64) << 14;
    const size_t baseB = ((size_t)(2 * z + 1) * 64) << 14;
    for (int c = 0; c < 64; ++c) {
        float4 va = *(const float4*)&GP[baseA + ((size_t)c << 14) + u];
        float4 vb = *(const float4*)&GP[baseB + ((size_t)c << 14) + u];
        ga.x += va.x; ga.y += va.y; ga.z += va.z; ga.w += va.w;
        gb.x += vb.x; gb.y += vb.y; gb.z += vb.z; gb.w += vb.w;
    }
    red[tid] = ga.x * gb.x + ga.y * gb.y + ga.z * gb.z + ga.w * gb.w;
    __syncthreads();
    for (int ss = 128; ss > 0; ss >>= 1) {
        if (tid < ss) red[tid] += red[tid + ss];
        __syncthreads();
    }
    if (tid == 0) atomicAdd(&scal[3 + z], red[0]);
}

// ---------------------------------------------------------------------------
// Scalar heads (z-batched): out[1 + z*BSZ + m] = dot(X[m], w) + b
// z: 0=(ISP,c1) 1=(ISH,c2) 2=(TSP,c4) 3=(TSH,c3)
// ---------------------------------------------------------------------------
__global__ void head4(const float* __restrict__ isp, const float* __restrict__ ish,
                      const float* __restrict__ tsp, const float* __restrict__ tsh,
                      const float* __restrict__ c1w, const float* __restrict__ c2w,
                      const float* __restrict__ c4w, const float* __restrict__ c3w,
                      const float* __restrict__ c1b, const float* __restrict__ c2b,
                      const float* __restrict__ c4b, const float* __restrict__ c3b,
                      float* __restrict__ out) {
    int z = blockIdx.y;
    const float* X = z == 0 ? isp : z == 1 ? ish : z == 2 ? tsp : tsh;
    const float* w = z == 0 ? c1w : z == 1 ? c2w : z == 2 ? c4w : c3w;
    const float* b = z == 0 ? c1b : z == 1 ? c2b : z == 2 ? c4b : c3b;
    int m = blockIdx.x * 256 + threadIdx.x;
    const float4* xp = (const float4*)(X + (size_t)m * 128);
    const float4* wp = (const float4*)w;
    float acc = 0.0f;
#pragma unroll
    for (int u = 0; u < 32; ++u) {
        float4 av = xp[u], cv = wp[u];
        acc += av.x * cv.x + av.y * cv.y + av.z * cv.z + av.w * cv.w;
    }
    out[1 + (size_t)z * BSZ + m] = acc + b[0];
}

__global__ void final_kernel(const float* __restrict__ scal, float* __restrict__ out) {
    float loss1 = scal[1];
    float loss_sh = scal[2];
    float ss_i = scal[3];
    float ss_t = scal[4];
    float loss_sp = 0.5f * (sqrtf(ss_t) + sqrtf(ss_i));
    out[0] = (loss_sp + loss_sh + loss1) / 3.0f;
}

// ---------------------------------------------------------------------------
extern "C" void kernel_launch(void* const* d_in, const int* in_sizes, int n_in,
                              void* d_out, int out_size, void* d_ws, size_t ws_size,
                              hipStream_t stream) {
    const float* i_in  = (const float*)d_in[0];
    const float* t_in  = (const float*)d_in[1];
    const int*   y     = (const int*)d_in[2];
    const float* l1_w  = (const float*)d_in[3];
    const float* l1_b  = (const float*)d_in[4];
    const float* l2_w  = (const float*)d_in[5];
    const float* l2_b  = (const float*)d_in[6];
    const float* l3_w  = (const float*)d_in[7];
    const float* l3_b  = (const float*)d_in[8];
    const float* tl1_w = (const float*)d_in[9];
    const float* tl1_b = (const float*)d_in[10];
    const float* tl2_w = (const float*)d_in[11];
    const float* tl2_b = (const float*)d_in[12];
    const float* isp_w = (const float*)d_in[13];
    const float* isp_b = (const float*)d_in[14];
    const float* ish_w = (const float*)d_in[15];
    const float* ish_b = (const float*)d_in[16];
    const float* tsh_w = (const float*)d_in[17];
    const float* tsh_b = (const float*)d_in[18];
    const float* tsp_w = (const float*)d_in[19];
    const float* tsp_b = (const float*)d_in[20];
    const float* c1_w  = (const float*)d_in[21];
    const float* c1_b  = (const float*)d_in[22];
    const float* c2_w  = (const float*)d_in[23];
    const float* c2_b  = (const float*)d_in[24];
    const float* c3_w  = (const float*)d_in[25];
    const float* c3_b  = (const float*)d_in[26];
    const float* c4_w  = (const float*)d_in[27];
    const float* c4_b  = (const float*)d_in[28];
    const float* scale1 = (const float*)d_in[29];
    const float* scale2 = (const float*)d_in[30];

    float* ws = (float*)d_ws;
    // zeroed fp32 region: SCAL only
    float* SCAL = ws;                       // 64
    // fp32 work buffers
    float* ISP  = ws + 64;
    float* ISH  = ISP + (size_t)BSZ * 128;
    float* TSP  = ISH + (size_t)BSZ * 128;
    float* TSH  = TSP + (size_t)BSZ * 128;
    // bf16 buffers
    unsigned short* IB   = (unsigned short*)(TSH + (size_t)BSZ * 128);
    unsigned short* WB   = IB + (size_t)BSZ * 2048;      // 1294336
    unsigned short* FI1B = WB + 1294336;                 // 4096*512
    unsigned short* FI2B = FI1B + (size_t)BSZ * 512;     // 4096*256
    unsigned short* FIB  = FI2B + (size_t)BSZ * 256;     // 4096*128
    unsigned short* FT1B = FIB + (size_t)BSZ * 128;
    unsigned short* FTB  = FT1B + (size_t)BSZ * 128;
    unsigned short* FINB = FTB + (size_t)BSZ * 128;
    unsigned short* FTNB = FINB + (size_t)BSZ * 128;
    unsigned short* ISHN = FTNB + (size_t)BSZ * 128;
    unsigned short* TSHN = ISHN + (size_t)BSZ * 128;
    // ST partial buffers ALIAS IB (16.8 MB): IB fully consumed by the L1
    // mfma_gemm before clip_mfma runs (stream order).
    float* ST1 = (float*)IB;                 // 1589248 floats
    float* ST2 = ST1 + ST_FLOATS;            // 1589248 floats
    // GP (gram split-K partials, 4*64*16384 = 4.19M floats = 16.8 MB) ALIASES
    // the same IB region: clip_finalize has consumed ST before gram_splitk
    // runs (stream order). 4.19M floats == IB size exactly.
    float* GP = (float*)IB;

    float* out = (float*)d_out;

    hipMemsetAsync(d_ws, 0, 64 * sizeof(float), stream);
    cast_kernel<<<8192, 256, 0, stream>>>(i_in, IB, BSZ * 2048);
    cast_w_kernel<<<1264, 256, 0, stream>>>(l1_w, l2_w, l3_w, tl2_w, isp_w, ish_w, tsh_w, tsp_w, WB);
    gemm_small<<<dim3(2, 64), dim3(16, 16), 0, stream>>>(t_in, tl1_w, tl1_b, FT1B, BSZ, 128, 49, 1);

    mfma_gemm<<<dim3(4, 32), 256, 0, stream>>>(IB, WB, l1_b, FI1B, nullptr, 512, 2048, 1);
    mfma_gemm<<<dim3(2, 32), 256, 0, stream>>>(FI1B, WB + 1048576, l2_b, FI2B, nullptr, 256, 512, 1);
    mfma_gemm<<<dim3(1, 32), 256, 0, stream>>>(FI2B, WB + 1179648, l3_b, FIB, nullptr, 128, 256, 0);
    mfma_gemm<<<dim3(1, 32), 256, 0, stream>>>(FT1B, WB + 1212416, tl2_b, FTB, nullptr, 128, 128, 0);
    mfma_heads<<<dim3(1, 32, 4), 256, 0, stream>>>(FIB, FTB, WB + 1228800, WB + 1245184, WB + 1261568,
                                                   WB + 1277952, isp_b, ish_b, tsh_b, tsp_b,
                                                   ISP, ISH, TSH, TSP);
    rownorm4<<<dim3(16, 4), 256, 0, stream>>>(FIB, FTB, ISH, TSH, FINB, FTNB, ISHN, TSHN);

    clip_mfma<<<dim3(32, 32, 2), 256, 0, stream>>>(FINB, FTNB, ISHN, TSHN, y, scale1, scale2, ST1, ST2);
    clip_finalize<<<dim3(16, 2), 256, 0, stream>>>(ST1, ST2, y, scale1, scale2, &SCAL[1]);

    gram_splitk<<<dim3(64, 4), 256, 0, stream>>>(ISP, ISH, TSP, TSH, GP);
    frob_combine<<<dim3(16, 2), 256, 0, stream>>>(GP, SCAL);
    head4<<<dim3(16, 4), 256, 0, stream>>>(ISP, ISH, TSP, TSH, c1_w, c2_w, c4_w, c3_w,
                                           c1_b, c2_b, c4_b, c3_b, out);
    final_kernel<<<1, 1, 0, stream>>>(SCAL, out);
}